// Round 2
// baseline (15249.332 us; speedup 1.0000x reference)
//
#include <hip/hip_runtime.h>
#include <math.h>

typedef unsigned short u16;
typedef unsigned int   u32;
typedef __attribute__((ext_vector_type(8))) short bf16x8;
typedef __attribute__((ext_vector_type(4))) float f32x4;

#define DEVI static __device__ __forceinline__

DEVI float bf2f(u16 u){ u32 x = ((u32)u) << 16; float f; __builtin_memcpy(&f, &x, 4); return f; }
DEVI u16 f2bf(float f){ u32 x; __builtin_memcpy(&x, &f, 4); u32 r = (x + 0x7fffu + ((x >> 16) & 1u)) >> 16; return (u16)r; }
DEVI float sigm(float x){ return 1.f / (1.f + __expf(-x)); }
DEVI float tanh_f(float x){ float e = __expf(2.f * x); return 1.f - 2.f / (e + 1.f); }

DEVI float blk_max(float v, float* sm){
#pragma unroll
  for (int m = 32; m; m >>= 1) v = fmaxf(v, __shfl_xor(v, m));
  __syncthreads();
  if ((threadIdx.x & 63) == 0) sm[threadIdx.x >> 6] = v;
  __syncthreads();
  return fmaxf(fmaxf(sm[0], sm[1]), fmaxf(sm[2], sm[3]));
}
DEVI float blk_sum(float v, float* sm){
#pragma unroll
  for (int m = 32; m; m >>= 1) v += __shfl_xor(v, m);
  __syncthreads();
  if ((threadIdx.x & 63) == 0) sm[threadIdx.x >> 6] = v;
  __syncthreads();
  return sm[0] + sm[1] + sm[2] + sm[3];
}

// ---------------- pack kernels ----------------
// Whh -> bf16 transposed [d][n][k]  (B^T for MFMA frag loads)
__global__ void k_pack_whh2(const float* __restrict__ Wf, const float* __restrict__ Wb, u16* __restrict__ out){
  int blk = blockIdx.x;             // 2*1024
  int d = blk >> 10, n = blk & 1023;
  const float* W = d ? Wb : Wf;
  int k = threadIdx.x;
  out[((size_t)d * 1024 + n) * 256 + k] = f2bf(W[(size_t)k * 1024 + n]);
}

// dec weights rows: k<512 -> Wih row 128+k (ctx part); else Whh row k-512. layout [k][j] gate-interleaved
__global__ void k_pack_decw(const float* __restrict__ Wih, const float* __restrict__ Whh, ushort4* __restrict__ out){
  int idx = blockIdx.x * 256 + threadIdx.x;      // 768*256
  int k = idx >> 8, j = idx & 255;
  const float* row = (k < 512) ? (Wih + (size_t)(128 + k) * 1024) : (Whh + (size_t)(k - 512) * 1024);
  ushort4 r;
  r.x = f2bf(row[j]);       r.y = f2bf(row[256 + j]);
  r.z = f2bf(row[512 + j]); r.w = f2bf(row[768 + j]);
  out[idx] = r;
}

// vocab_W f32 -> bf16 (same layout)
__global__ void k_pack_vw(const float* __restrict__ in, u16* __restrict__ out){
  int i = blockIdx.x * 256 + threadIdx.x;        // x4 elements
  float4 v = ((const float4*)in)[i];
  ushort4 o;
  o.x = f2bf(v.x); o.y = f2bf(v.y); o.z = f2bf(v.z); o.w = f2bf(v.w);
  ((ushort4*)out)[i] = o;
}

// ---------------- encoder ----------------
// xw[d][s][n][b] bf16 of emb@Wih + bias   (n = gate*256 + hc)
__global__ __launch_bounds__(256) void k_enc_pre2(const int* __restrict__ src, const float* __restrict__ emb,
                          const float* __restrict__ Wf, const float* __restrict__ bf_,
                          const float* __restrict__ Wb, const float* __restrict__ bb_,
                          u16* __restrict__ xw){
  int d = blockIdx.x / 400, s = blockIdx.x % 400;
  const float* Wih = d ? Wb : Wf; const float* bias = d ? bb_ : bf_;
  __shared__ float es[16][128];
  int tid = threadIdx.x;
  for (int idx = tid; idx < 16 * 128; idx += 256){
    int b = idx >> 7, e = idx & 127;
    es[b][e] = emb[(size_t)src[b * 400 + s] * 128 + e];
  }
  __syncthreads();
  int j = tid;
  float a[4][16];
#pragma unroll
  for (int g = 0; g < 4; ++g){
    float bv = bias[g * 256 + j];
#pragma unroll
    for (int b = 0; b < 16; ++b) a[g][b] = bv;
  }
  for (int e4 = 0; e4 < 32; ++e4){
    float w0[4], w1[4], w2[4], w3[4];
#pragma unroll
    for (int u = 0; u < 4; ++u){
      int e = e4 * 4 + u;
      w0[u] = Wih[(size_t)e * 1024 + j];
      w1[u] = Wih[(size_t)e * 1024 + 256 + j];
      w2[u] = Wih[(size_t)e * 1024 + 512 + j];
      w3[u] = Wih[(size_t)e * 1024 + 768 + j];
    }
#pragma unroll
    for (int b = 0; b < 16; ++b){
      float4 x = *(const float4*)&es[b][e4 * 4];
      a[0][b] += x.x * w0[0] + x.y * w0[1] + x.z * w0[2] + x.w * w0[3];
      a[1][b] += x.x * w1[0] + x.y * w1[1] + x.z * w1[2] + x.w * w1[3];
      a[2][b] += x.x * w2[0] + x.y * w2[1] + x.z * w2[2] + x.w * w2[3];
      a[3][b] += x.x * w3[0] + x.y * w3[1] + x.z * w3[2] + x.w * w3[3];
    }
  }
#pragma unroll
  for (int g = 0; g < 4; ++g){
    u16 tmp[16];
#pragma unroll
    for (int b = 0; b < 16; ++b) tmp[b] = f2bf(a[g][b]);
    uint4* dst = (uint4*)&xw[(((size_t)(d * 400 + s)) * 1024 + g * 256 + j) * 16];
    dst[0] = *(uint4*)&tmp[0];
    dst[1] = *(uint4*)&tmp[8];
  }
}

// MFMA-batched bidirectional LSTM: 1 block per direction, 8 waves.
// A = h[16 batch][256] (hi+lo bf16 in LDS), B = Whh^T [n][k] (kb0-1 regs, kb2-7 streamed).
__global__ __launch_bounds__(512, 2) void k_enc_lstm2(
    const u16* __restrict__ xw, const u16* __restrict__ wpk,
    u16* __restrict__ enc_out, float* __restrict__ hfin, float* __restrict__ cfin)
{
  const int d = blockIdx.x;
  const int tid = threadIdx.x;
  const int w = tid >> 6;
  const int lane = tid & 63;
  const int q = lane & 15, r = lane >> 4;

  __shared__ u16 hhi[16][264];
  __shared__ u16 hlo[16][264];
  for (int idx = tid; idx < 16 * 264; idx += 512){
    hhi[idx / 264][idx % 264] = 0;
    hlo[idx / 264][idx % 264] = 0;
  }

  const u16* wb = wpk + (size_t)d * 1024 * 256;
  int nn[8];
  bf16x8 br0[8], br1[8];
#pragma unroll
  for (int t = 0; t < 8; ++t){
    int ch = t >> 2, g = t & 3;
    nn[t] = g * 256 + w * 32 + ch * 16 + q;
    br0[t] = *(const bf16x8*)&wb[(size_t)nn[t] * 256 + 0 * 32 + r * 8];
    br1[t] = *(const bf16x8*)&wb[(size_t)nn[t] * 256 + 1 * 32 + r * 8];
  }
  float c[8], hl[8];
#pragma unroll
  for (int i = 0; i < 8; ++i){ c[i] = 0.f; hl[i] = 0.f; }
  __syncthreads();

  for (int it = 0; it < 400; ++it){
    int s = d ? (399 - it) : it;
    f32x4 acc[8];
    const u16* xb = xw + ((size_t)(d * 400 + s)) * 1024 * 16;
#pragma unroll
    for (int t = 0; t < 8; ++t){
      ushort4 xv = *(const ushort4*)&xb[nn[t] * 16 + 4 * r];
      f32x4 v;
      v[0] = bf2f(xv.x); v[1] = bf2f(xv.y); v[2] = bf2f(xv.z); v[3] = bf2f(xv.w);
      acc[t] = v;
    }

    bf16x8 sA[8], sB[8];
#define LOADS(BUF, KB) \
    _Pragma("unroll") for (int t = 0; t < 8; ++t) \
      BUF[t] = *(const bf16x8*)&wb[(size_t)nn[t] * 256 + (KB) * 32 + r * 8];

    bf16x8 ahC = *(const bf16x8*)&hhi[q][0 * 32 + r * 8];
    bf16x8 alC = *(const bf16x8*)&hlo[q][0 * 32 + r * 8];
#define MMSTEP(KB, BUF) { \
    bf16x8 ahN, alN; \
    if ((KB) < 7){ ahN = *(const bf16x8*)&hhi[q][((KB)+1) * 32 + r * 8]; \
                   alN = *(const bf16x8*)&hlo[q][((KB)+1) * 32 + r * 8]; } \
    _Pragma("unroll") for (int t = 0; t < 8; ++t){ \
      acc[t] = __builtin_amdgcn_mfma_f32_16x16x32_bf16(ahC, BUF[t], acc[t], 0, 0, 0); \
      acc[t] = __builtin_amdgcn_mfma_f32_16x16x32_bf16(alC, BUF[t], acc[t], 0, 0, 0); } \
    if ((KB) < 7){ ahC = ahN; alC = alN; } }

    LOADS(sA, 2)
    MMSTEP(0, br0)
    MMSTEP(1, br1)
    LOADS(sB, 3)  MMSTEP(2, sA)
    LOADS(sA, 4)  MMSTEP(3, sB)
    LOADS(sB, 5)  MMSTEP(4, sA)
    LOADS(sA, 6)  MMSTEP(5, sB)
    LOADS(sB, 7)  MMSTEP(6, sA)
    MMSTEP(7, sB)
#undef LOADS
#undef MMSTEP

    // gates
#pragma unroll
    for (int ch = 0; ch < 2; ++ch){
#pragma unroll
      for (int rg = 0; rg < 4; ++rg){
        float pi = acc[ch * 4 + 0][rg], pf = acc[ch * 4 + 1][rg];
        float pg = acc[ch * 4 + 2][rg], po = acc[ch * 4 + 3][rg];
        int ci = ch * 4 + rg;
        float cv = sigm(pf) * c[ci] + sigm(pi) * tanh_f(pg);
        float hv = sigm(po) * tanh_f(cv);
        c[ci] = cv; hl[ci] = hv;
      }
    }
    __syncthreads();   // all A-reads of this step complete
#pragma unroll
    for (int ch = 0; ch < 2; ++ch){
      int hc = w * 32 + ch * 16 + q;
#pragma unroll
      for (int rg = 0; rg < 4; ++rg){
        int b = 4 * r + rg;
        float hv = hl[ch * 4 + rg];
        u16 hi = f2bf(hv);
        float hif = bf2f(hi);
        u16 lo = f2bf(hv - hif);
        hhi[b][hc] = hi; hlo[b][hc] = lo;
        enc_out[((size_t)b * 400 + s) * 512 + d * 256 + hc] = hi;
      }
    }
    __syncthreads();   // writes visible for next step
  }
#pragma unroll
  for (int ch = 0; ch < 2; ++ch){
    int hc = w * 32 + ch * 16 + q;
#pragma unroll
    for (int rg = 0; rg < 4; ++rg){
      int b = 4 * r + rg;
      hfin[(d * 16 + b) * 256 + hc] = hl[ch * 4 + rg];
      cfin[(d * 16 + b) * 256 + hc] = c[ch * 4 + rg];
    }
  }
}

__global__ void k_reduce(const float* __restrict__ hfin, const float* __restrict__ cfin,
                         const float* __restrict__ rhW, const float* __restrict__ rhb,
                         const float* __restrict__ rcW, const float* __restrict__ rcb,
                         float* __restrict__ h0, float* __restrict__ c0){
  int b = blockIdx.x, j = threadIdx.x;
  float ah = rhb[j], ac = rcb[j];
  for (int k = 0; k < 256; ++k){
    float hv = hfin[b * 256 + k], cv = cfin[b * 256 + k];
    ah += hv * rhW[k * 256 + j];
    ac += cv * rcW[k * 256 + j];
  }
  for (int k = 0; k < 256; ++k){
    float hv = hfin[(16 + b) * 256 + k], cv = cfin[(16 + b) * 256 + k];
    ah += hv * rhW[(256 + k) * 256 + j];
    ac += cv * rcW[(256 + k) * 256 + j];
  }
  h0[b * 256 + j] = tanh_f(ah);
  c0[b * 256 + j] = tanh_f(ac);
}

// enc_feat[b][s][j] = enc_out[b][s][:512] @ attn_Wh  (bf16 out)
__global__ void k_encfeat(const u16* __restrict__ enc_out, const float* __restrict__ Wh, u16* __restrict__ feat){
  int blk = blockIdx.x; int b = blk / 25; int sc = blk % 25;
  int j = threadIdx.x;
  float acc[16];
#pragma unroll
  for (int i = 0; i < 16; ++i) acc[i] = 0.f;
  const u32* ebase = (const u32*)(enc_out + ((size_t)b * 400 + sc * 16) * 512);
  for (int k2 = 0; k2 < 256; ++k2){
    float wa = Wh[(2 * k2) * 256 + j], wb_ = Wh[(2 * k2 + 1) * 256 + j];
#pragma unroll
    for (int ss = 0; ss < 16; ++ss){
      u32 p = ebase[ss * 256 + k2];
      acc[ss] += bf2f((u16)(p & 0xffff)) * wa + bf2f((u16)(p >> 16)) * wb_;
    }
  }
#pragma unroll
  for (int ss = 0; ss < 16; ++ss)
    feat[((size_t)b * 400 + sc * 16 + ss) * 256 + j] = f2bf(acc[ss]);
}

// ---------------- decoder precompute ----------------
__global__ void k_dec_pre(const int* __restrict__ din, const float* __restrict__ emb,
                          const float* __restrict__ Wih, const float* __restrict__ db,
                          const float* __restrict__ pgW,
                          float4* __restrict__ xwd, float* __restrict__ pg_emb){
  int blk = blockIdx.x; int t = blk / 16, b = blk % 16;
  int j = threadIdx.x;
  int id = din[b * 50 + t];
  const float* er = emb + (size_t)id * 128;
  float a0 = db[j], a1 = db[256 + j], a2 = db[512 + j], a3 = db[768 + j];
  for (int e = 0; e < 128; ++e){
    float x = er[e];
    const float* wr = Wih + (size_t)e * 1024;
    a0 += x * wr[j]; a1 += x * wr[256 + j]; a2 += x * wr[512 + j]; a3 += x * wr[768 + j];
  }
  xwd[(size_t)blk * 256 + j] = make_float4(a0, a1, a2, a3);
  __shared__ float red[256];
  float pe = 0.f;
  if (j < 128) pe = er[j] * pgW[768 + j];
  red[j] = pe; __syncthreads();
  for (int off = 128; off; off >>= 1){ if (j < off) red[j] += red[j + off]; __syncthreads(); }
  if (j == 0) pg_emb[blk] = red[0];
}

// ---------------- decoder step kernels ----------------
__global__ __launch_bounds__(256) void k_cell(const float* __restrict__ adec, const float* __restrict__ hin,
                                              const float* __restrict__ cin, const ushort4* __restrict__ Wp,
                                              const float4* __restrict__ xwd, int t,
                                              float* __restrict__ hout, float* __restrict__ cout,
                                              float* __restrict__ adec_h){
  int hcbase = blockIdx.x * 4;
  int tid = threadIdx.x;
  int b = tid & 15, hcl = (tid >> 4) & 3, ks = tid >> 6;
  __shared__ float a_lds[16][772];
  __shared__ float part[4][16][4][4];
  for (int idx = tid; idx < 16 * 512; idx += 256)
    a_lds[idx >> 9][idx & 511] = adec[(idx >> 9) * 768 + (idx & 511)];
  for (int idx = tid; idx < 16 * 256; idx += 256)
    a_lds[idx >> 8][512 + (idx & 255)] = hin[idx];
  __syncthreads();
  int hc = hcbase + hcl;
  float g0 = 0.f, g1 = 0.f, g2 = 0.f, g3 = 0.f;
  const ushort4* wb = Wp + hc;
  const float* arow = a_lds[b];
  for (int k = ks * 192; k < ks * 192 + 192; k += 4){
    float4 av = *(const float4*)(arow + k);
    ushort4 w0 = wb[(k + 0) * 256];
    ushort4 w1 = wb[(k + 1) * 256];
    ushort4 w2 = wb[(k + 2) * 256];
    ushort4 w3 = wb[(k + 3) * 256];
    g0 += av.x * bf2f(w0.x) + av.y * bf2f(w1.x) + av.z * bf2f(w2.x) + av.w * bf2f(w3.x);
    g1 += av.x * bf2f(w0.y) + av.y * bf2f(w1.y) + av.z * bf2f(w2.y) + av.w * bf2f(w3.y);
    g2 += av.x * bf2f(w0.z) + av.y * bf2f(w1.z) + av.z * bf2f(w2.z) + av.w * bf2f(w3.z);
    g3 += av.x * bf2f(w0.w) + av.y * bf2f(w1.w) + av.z * bf2f(w2.w) + av.w * bf2f(w3.w);
  }
  part[ks][b][hcl][0] = g0; part[ks][b][hcl][1] = g1;
  part[ks][b][hcl][2] = g2; part[ks][b][hcl][3] = g3;
  __syncthreads();
  if (tid < 64){
    int b2 = tid & 15, h2 = tid >> 4;
    float4 xv = xwd[((size_t)t * 16 + b2) * 256 + hcbase + h2];
    float s0 = xv.x + part[0][b2][h2][0] + part[1][b2][h2][0] + part[2][b2][h2][0] + part[3][b2][h2][0];
    float s1 = xv.y + part[0][b2][h2][1] + part[1][b2][h2][1] + part[2][b2][h2][1] + part[3][b2][h2][1];
    float s2 = xv.z + part[0][b2][h2][2] + part[1][b2][h2][2] + part[2][b2][h2][2] + part[3][b2][h2][2];
    float s3 = xv.w + part[0][b2][h2][3] + part[1][b2][h2][3] + part[2][b2][h2][3] + part[3][b2][h2][3];
    float iv = sigm(s0), fv = sigm(s1), gv = tanh_f(s2), ov = sigm(s3);
    int hcg = hcbase + h2;
    float cv = fv * cin[b2 * 256 + hcg] + iv * gv;
    float hv = ov * tanh_f(cv);
    cout[b2 * 256 + hcg] = cv;
    hout[b2 * 256 + hcg] = hv;
    adec_h[b2 * 768 + hcg] = hv;
  }
}

__global__ __launch_bounds__(256) void k_attn(const float* __restrict__ hnew, const u16* __restrict__ feat,
    const u16* __restrict__ enc_out, const int* __restrict__ src, const int* __restrict__ src_ext,
    const int* __restrict__ tgt_ext, const float* __restrict__ Ws, const float* __restrict__ Wsb,
    const float* __restrict__ Wc, const float* __restrict__ av_, const float* __restrict__ pgW,
    const float* __restrict__ pg_emb, const float* __restrict__ pgb, const float* __restrict__ pgbias,
    float* __restrict__ coverage, float* __restrict__ adec,
    float* __restrict__ pg_g, float* __restrict__ cvl_g, float* __restrict__ sct_g, int t){
  int b = blockIdx.x; int tid = threadIdx.x;
  __shared__ float hws_s[256];
  __shared__ float sc_s[400];
  __shared__ float at_s[400];
  __shared__ float ctx_s[512];
  __shared__ float red_s[4];
  {
    float acc = Wsb[tid];
    const float* hb_ = hnew + b * 256;
    for (int k = 0; k < 256; ++k) acc += hb_[k] * Ws[k * 256 + tid];
    hws_s[tid] = acc;
  }
  __syncthreads();
  {
    int w = tid >> 6, L = tid & 63;
    float4 hw = *(const float4*)&hws_s[4 * L];
    float4 wc = *(const float4*)&Wc[4 * L];
    float4 vv = *(const float4*)&av_[4 * L];
    for (int s = w; s < 400; s += 4){
      float cv = coverage[b * 400 + s];
      const u16* fp = feat + ((size_t)b * 400 + s) * 256 + 4 * L;
      u32 p0 = *(const u32*)fp; u32 p1 = *(const u32*)(fp + 2);
      float f0 = bf2f((u16)(p0 & 0xffff)) + hw.x + cv * wc.x;
      float f1 = bf2f((u16)(p0 >> 16))    + hw.y + cv * wc.y;
      float f2 = bf2f((u16)(p1 & 0xffff)) + hw.z + cv * wc.z;
      float f3 = bf2f((u16)(p1 >> 16))    + hw.w + cv * wc.w;
      float sc = tanh_f(f0) * vv.x + tanh_f(f1) * vv.y + tanh_f(f2) * vv.z + tanh_f(f3) * vv.w;
#pragma unroll
      for (int m = 32; m; m >>= 1) sc += __shfl_xor(sc, m);
      if (L == 0) sc_s[s] = (src[b * 400 + s] == 0) ? -1e9f : sc;
    }
  }
  __syncthreads();
  {
    float m = -1e30f;
    for (int s = tid; s < 400; s += 256) m = fmaxf(m, sc_s[s]);
    float mx = blk_max(m, red_s);
    float e = 0.f;
    for (int s = tid; s < 400; s += 256){ float ee = __expf(sc_s[s] - mx); at_s[s] = ee; e += ee; }
    float sum = blk_sum(e, red_s);
    float inv = 1.f / sum;
    for (int s = tid; s < 400; s += 256) at_s[s] *= inv;
  }
  __syncthreads();
  {
    float a0 = 0.f, a1 = 0.f;
    const u16* eb = enc_out + (size_t)b * 400 * 512;
    for (int sq = 0; sq < 100; ++sq){
      float4 aq = *(const float4*)&at_s[4 * sq];
      const u16* r0 = eb + (size_t)(4 * sq) * 512;
      a0 += aq.x * bf2f(r0[tid])        + aq.y * bf2f(r0[512 + tid])
          + aq.z * bf2f(r0[1024 + tid]) + aq.w * bf2f(r0[1536 + tid]);
      a1 += aq.x * bf2f(r0[256 + tid])  + aq.y * bf2f(r0[768 + tid])
          + aq.z * bf2f(r0[1280 + tid]) + aq.w * bf2f(r0[1792 + tid]);
    }
    ctx_s[tid] = a0; ctx_s[256 + tid] = a1;
    adec[b * 768 + tid] = a0; adec[b * 768 + 256 + tid] = a1;
  }
  float clp = 0.f, scp = 0.f;
  {
    int tg = tgt_ext[b * 50 + t];
    for (int s = tid; s < 400; s += 256){
      float a = at_s[s];
      float cv = coverage[b * 400 + s];
      clp += fminf(a, cv);
      coverage[b * 400 + s] = cv + a;
      if (src_ext[b * 400 + s] == tg) scp += a;
    }
  }
  __syncthreads();
  {
    float p = ctx_s[tid] * pgW[tid] + ctx_s[256 + tid] * pgW[256 + tid] + hnew[b * 256 + tid] * pgW[512 + tid];
    float dsum = blk_sum(p, red_s);
    float cl = blk_sum(clp, red_s);
    float sc2 = blk_sum(scp, red_s);
    if (tid == 0){
      float pg = sigm(dsum + pg_emb[t * 16 + b] + pgb[0] + pgbias[0]);
      pg = fminf(fmaxf(pg, 0.1f), 0.9f);
      pg_g[b] = pg; cvl_g[b] = cl; sct_g[b] = sc2;
    }
  }
}

__global__ __launch_bounds__(256) void k_vocab(const float* __restrict__ adec, const float* __restrict__ vW,
    const float* __restrict__ vb, const int* __restrict__ tgt_ext, int t,
    float* __restrict__ mpart, float* __restrict__ spart, float* __restrict__ ltgt){
  int col0 = blockIdx.x * 128;
  int tid = threadIdx.x;
  int cl = tid & 127, half = tid >> 7;
  int col = col0 + cl;
  float acc[16];
#pragma unroll
  for (int i = 0; i < 16; ++i) acc[i] = 0.f;
  const float* Wc = vW + col;
  for (int k = half * 384; k < half * 384 + 384; k += 4){
    float w0 = Wc[(size_t)(k + 0) * 32000];
    float w1 = Wc[(size_t)(k + 1) * 32000];
    float w2 = Wc[(size_t)(k + 2) * 32000];
    float w3 = Wc[(size_t)(k + 3) * 32000];
#pragma unroll
    for (int b = 0; b < 16; ++b){
      const float* Ab = adec + b * 768 + k;
      acc[b] += Ab[0] * w0 + Ab[1] * w1 + Ab[2] * w2 + Ab[3] * w3;
    }
  }
  __shared__ float Ls[2][16][128];
#pragma unroll
  for (int b2 = 0; b2 < 16; ++b2) Ls[half][b2][cl] = acc[b2];
  __syncthreads();
  if (half == 0){
    float vbc = vb[col];
#pragma unroll
    for (int b2 = 0; b2 < 16; ++b2) Ls[0][b2][cl] = Ls[0][b2][cl] + Ls[1][b2][cl] + vbc;
  }
  __syncthreads();
  {
    int b2 = tid >> 4, l16 = tid & 15;
    float m = -1e30f, ssum = 0.f;
#pragma unroll
    for (int i = 0; i < 8; ++i){
      float x = Ls[0][b2][l16 + 16 * i];
      float M = fmaxf(m, x);
      ssum = ssum * __expf(m - M) + __expf(x - M);
      m = M;
    }
#pragma unroll
    for (int mk = 1; mk < 16; mk <<= 1){
      float om = __shfl_xor(m, mk), os = __shfl_xor(ssum, mk);
      float M = fmaxf(m, om);
      ssum = ssum * __expf(m - M) + os * __expf(om - M);
      m = M;
    }
    if (l16 == 0){ mpart[b2 * 250 + blockIdx.x] = m; spart[b2 * 250 + blockIdx.x] = ssum; }
  }
  if (tid < 16){
    int tg = tgt_ext[tid * 50 + t];
    unsigned offc = (unsigned)(tg - col0);
    if (offc < 128u) ltgt[tid] = Ls[0][tid][offc];
  }
}

__global__ __launch_bounds__(256) void k_vocab_bf(const float* __restrict__ adec, const u16* __restrict__ vW,
    const float* __restrict__ vb, const int* __restrict__ tgt_ext, int t,
    float* __restrict__ mpart, float* __restrict__ spart, float* __restrict__ ltgt){
  int col0 = blockIdx.x * 128;
  int tid = threadIdx.x;
  int cl = tid & 127, half = tid >> 7;
  int col = col0 + cl;
  float acc[16];
#pragma unroll
  for (int i = 0; i < 16; ++i) acc[i] = 0.f;
  const u16* Wc = vW + col;
  for (int k = half * 384; k < half * 384 + 384; k += 4){
    float w0 = bf2f(Wc[(size_t)(k + 0) * 32000]);
    float w1 = bf2f(Wc[(size_t)(k + 1) * 32000]);
    float w2 = bf2f(Wc[(size_t)(k + 2) * 32000]);
    float w3 = bf2f(Wc[(size_t)(k + 3) * 32000]);
#pragma unroll
    for (int b = 0; b < 16; ++b){
      const float* Ab = adec + b * 768 + k;
      acc[b] += Ab[0] * w0 + Ab[1] * w1 + Ab[2] * w2 + Ab[3] * w3;
    }
  }
  __shared__ float Ls[2][16][128];
#pragma unroll
  for (int b2 = 0; b2 < 16; ++b2) Ls[half][b2][cl] = acc[b2];
  __syncthreads();
  if (half == 0){
    float vbc = vb[col];
#pragma unroll
    for (int b2 = 0; b2 < 16; ++b2) Ls[0][b2][cl] = Ls[0][b2][cl] + Ls[1][b2][cl] + vbc;
  }
  __syncthreads();
  {
    int b2 = tid >> 4, l16 = tid & 15;
    float m = -1e30f, ssum = 0.f;
#pragma unroll
    for (int i = 0; i < 8; ++i){
      float x = Ls[0][b2][l16 + 16 * i];
      float M = fmaxf(m, x);
      ssum = ssum * __expf(m - M) + __expf(x - M);
      m = M;
    }
#pragma unroll
    for (int mk = 1; mk < 16; mk <<= 1){
      float om = __shfl_xor(m, mk), os = __shfl_xor(ssum, mk);
      float M = fmaxf(m, om);
      ssum = ssum * __expf(m - M) + os * __expf(om - M);
      m = M;
    }
    if (l16 == 0){ mpart[b2 * 250 + blockIdx.x] = m; spart[b2 * 250 + blockIdx.x] = ssum; }
  }
  if (tid < 16){
    int tg = tgt_ext[tid * 50 + t];
    unsigned offc = (unsigned)(tg - col0);
    if (offc < 128u) ltgt[tid] = Ls[0][tid][offc];
  }
}

__global__ void k_comb(const float* __restrict__ mpart, const float* __restrict__ spart,
                       const float* __restrict__ ltgt, const float* __restrict__ pg_g,
                       const float* __restrict__ cvl_g, const float* __restrict__ sct_g,
                       const int* __restrict__ tgt_ext, const float* __restrict__ lam, int t,
                       float* __restrict__ loss_g, float* __restrict__ valid_g){
  int tid = threadIdx.x;
  int b = tid >> 4, l16 = tid & 15;
  float m = -1e30f, s = 0.f;
  for (int i = l16; i < 250; i += 16){
    float om = mpart[b * 250 + i], os = spart[b * 250 + i];
    float M = fmaxf(m, om);
    s = s * __expf(m - M) + os * __expf(om - M);
    m = M;
  }
#pragma unroll
  for (int mk = 1; mk < 16; mk <<= 1){
    float om = __shfl_xor(m, mk), os = __shfl_xor(s, mk);
    float M = fmaxf(m, om);
    s = s * __expf(m - M) + os * __expf(om - M);
    m = M;
  }
  if (l16 == 0){
    int tg = tgt_ext[b * 50 + t];
    float pv = (tg < 32000) ? (__expf(ltgt[b] - m) / s) : 0.f;
    float pg = pg_g[b];
    float pf = pg * pv + (1.f - pg) * sct_g[b];
    float sl = -__logf(pf + 1e-12f);
    float msk = (tg != 0) ? 1.f : 0.f;
    loss_g[t * 16 + b] = (sl + lam[0] * cvl_g[b]) * msk;
    valid_g[t * 16 + b] = msk;
  }
}

__global__ void k_final(const float* __restrict__ loss_g, const float* __restrict__ valid_g, float* __restrict__ out){
  __shared__ float r1[256], r2[256];
  int tid = threadIdx.x;
  float a = 0.f, v = 0.f;
  for (int i = tid; i < 800; i += 256){ a += loss_g[i]; v += valid_g[i]; }
  r1[tid] = a; r2[tid] = v; __syncthreads();
  for (int off = 128; off; off >>= 1){
    if (tid < off){ r1[tid] += r1[tid + off]; r2[tid] += r2[tid + off]; }
    __syncthreads();
  }
  if (tid == 0) out[0] = r1[0] / fmaxf(r2[0], 1.f);
}

extern "C" void kernel_launch(void* const* d_in, const int* in_sizes, int n_in,
                              void* d_out, int out_size, void* d_ws, size_t ws_size,
                              hipStream_t stream){
  const int*   src     = (const int*)  d_in[0];
  const int*   src_ext = (const int*)  d_in[1];
  const int*   dec_in  = (const int*)  d_in[2];
  const int*   tgt_ext = (const int*)  d_in[3];
  const float* enc_emb = (const float*)d_in[5];
  const float* eWihF   = (const float*)d_in[6];
  const float* eWhhF   = (const float*)d_in[7];
  const float* ebF     = (const float*)d_in[8];
  const float* eWihB   = (const float*)d_in[9];
  const float* eWhhB   = (const float*)d_in[10];
  const float* ebB     = (const float*)d_in[11];
  const float* rhW     = (const float*)d_in[12];
  const float* rhb     = (const float*)d_in[13];
  const float* rcW     = (const float*)d_in[14];
  const float* rcb     = (const float*)d_in[15];
  const float* dec_emb = (const float*)d_in[16];
  const float* dWih    = (const float*)d_in[17];
  const float* dWhh    = (const float*)d_in[18];
  const float* db_     = (const float*)d_in[19];
  const float* aWh     = (const float*)d_in[20];
  const float* aWs     = (const float*)d_in[21];
  const float* aWsb    = (const float*)d_in[22];
  const float* aWc     = (const float*)d_in[23];
  const float* av      = (const float*)d_in[24];
  const float* pgW     = (const float*)d_in[25];
  const float* pgb     = (const float*)d_in[26];
  const float* vW      = (const float*)d_in[27];
  const float* vb      = (const float*)d_in[28];
  const float* lam     = (const float*)d_in[29];
  const float* pgbias  = (const float*)d_in[30];
  (void)in_sizes; (void)n_in; (void)out_size;

  char* w = (char*)d_ws;
  size_t off = 0;
  auto alloc = [&](size_t bytes) -> char* {
    char* p = w + off; off += (bytes + 255) & ~(size_t)255; return p;
  };
  u16*     xw     = (u16*)    alloc(2ull * 400 * 1024 * 16 * 2);  // 26.2 MB [d][s][n][b]
  u16*     whhp   = (u16*)    alloc(2ull * 1024 * 256 * 2);       // 1.05 MB [d][n][k]
  ushort4* decwp  = (ushort4*)alloc(768ull * 256 * 8);            // 1.57 MB
  u16*     enc_out= (u16*)    alloc(16ull * 400 * 512 * 2);       // 6.55 MB
  u16*     feat   = (u16*)    alloc(16ull * 400 * 256 * 2);       // 3.28 MB
  float*   hfin   = (float*)  alloc(2 * 16 * 256 * 4);
  float*   cfin   = (float*)  alloc(2 * 16 * 256 * 4);
  float*   hbuf   = (float*)  alloc(2 * 16 * 256 * 4);
  float*   cbuf   = (float*)  alloc(2 * 16 * 256 * 4);
  float4*  xwd    = (float4*) alloc(50ull * 16 * 256 * 16);       // 3.28 MB
  float*   pg_emb = (float*)  alloc(800 * 4);
  float*   coverage=(float*)  alloc(16 * 400 * 4);
  float*   adec   = (float*)  alloc(16 * 768 * 4);
  float*   mpart  = (float*)  alloc(16 * 250 * 4);
  float*   spart  = (float*)  alloc(16 * 250 * 4);
  float*   ltgt   = (float*)  alloc(64);
  float*   pg_g   = (float*)  alloc(64);
  float*   cvl_g  = (float*)  alloc(64);
  float*   sct_g  = (float*)  alloc(64);
  float*   loss_g = (float*)  alloc(800 * 4);
  float*   valid_g= (float*)  alloc(800 * 4);
  size_t off_novw = off;
  u16*     vWb    = (u16*)    alloc(768ull * 32000 * 2);          // 49.2 MB
  bool use_bf16_vocab = (off <= ws_size);
  (void)off_novw;

  hipMemsetAsync(coverage, 0, 16 * 400 * 4 + 16 * 768 * 4, stream);

  hipLaunchKernelGGL(k_pack_whh2, dim3(2048),  dim3(256), 0, stream, eWhhF, eWhhB, whhp);
  hipLaunchKernelGGL(k_pack_decw, dim3(768),   dim3(256), 0, stream, dWih, dWhh, decwp);
  if (use_bf16_vocab)
    hipLaunchKernelGGL(k_pack_vw, dim3(24000), dim3(256), 0, stream, vW, vWb);
  hipLaunchKernelGGL(k_enc_pre2,  dim3(800),   dim3(256), 0, stream, src, enc_emb, eWihF, ebF, eWihB, ebB, xw);
  hipLaunchKernelGGL(k_dec_pre,   dim3(800),   dim3(256), 0, stream, dec_in, dec_emb, dWih, db_, pgW, xwd, pg_emb);
  hipLaunchKernelGGL(k_enc_lstm2, dim3(2),     dim3(512), 0, stream, xw, whhp, enc_out, hfin, cfin);
  hipLaunchKernelGGL(k_reduce,    dim3(16),    dim3(256), 0, stream, hfin, cfin, rhW, rhb, rcW, rcb, hbuf, cbuf);
  hipLaunchKernelGGL(k_encfeat,   dim3(400),   dim3(256), 0, stream, enc_out, aWh, feat);

  for (int t = 0; t < 50; ++t){
    float* hin  = hbuf + (t & 1) * 16 * 256;
    float* hout = hbuf + ((t + 1) & 1) * 16 * 256;
    float* cin  = cbuf + (t & 1) * 16 * 256;
    float* cout = cbuf + ((t + 1) & 1) * 16 * 256;
    hipLaunchKernelGGL(k_cell,  dim3(64),  dim3(256), 0, stream, adec, hin, cin, decwp, xwd, t, hout, cout, adec + 512);
    hipLaunchKernelGGL(k_attn,  dim3(16),  dim3(256), 0, stream, hout, feat, enc_out, src, src_ext, tgt_ext,
                       aWs, aWsb, aWc, av, pgW, pg_emb, pgb, pgbias, coverage, adec, pg_g, cvl_g, sct_g, t);
    if (use_bf16_vocab)
      hipLaunchKernelGGL(k_vocab_bf, dim3(250), dim3(256), 0, stream, adec, vWb, vb, tgt_ext, t, mpart, spart, ltgt);
    else
      hipLaunchKernelGGL(k_vocab, dim3(250), dim3(256), 0, stream, adec, vW, vb, tgt_ext, t, mpart, spart, ltgt);
    hipLaunchKernelGGL(k_comb,  dim3(1),   dim3(256), 0, stream, mpart, spart, ltgt, pg_g, cvl_g, sct_g, tgt_ext, lam, t, loss_g, valid_g);
  }
  hipLaunchKernelGGL(k_final, dim3(1), dim3(256), 0, stream, loss_g, valid_g, (float*)d_out);
}

// Round 3
// 8476.334 us; speedup vs baseline: 1.7990x; 1.7990x over previous
//
#include <hip/hip_runtime.h>
#include <math.h>

typedef unsigned short u16;
typedef unsigned int   u32;
typedef __attribute__((ext_vector_type(8))) short bf16x8;
typedef __attribute__((ext_vector_type(4))) float f32x4;

#define DEVI static __device__ __forceinline__

DEVI float bf2f(u16 u){ u32 x = ((u32)u) << 16; float f; __builtin_memcpy(&f, &x, 4); return f; }
DEVI u16 f2bf(float f){ u32 x; __builtin_memcpy(&x, &f, 4); u32 r = (x + 0x7fffu + ((x >> 16) & 1u)) >> 16; return (u16)r; }
DEVI float sigm(float x){ return 1.f / (1.f + __expf(-x)); }
DEVI float tanh_f(float x){ float e = __expf(2.f * x); return 1.f - 2.f / (e + 1.f); }

DEVI float blk_max(float v, float* sm){
#pragma unroll
  for (int m = 32; m; m >>= 1) v = fmaxf(v, __shfl_xor(v, m));
  __syncthreads();
  if ((threadIdx.x & 63) == 0) sm[threadIdx.x >> 6] = v;
  __syncthreads();
  return fmaxf(fmaxf(sm[0], sm[1]), fmaxf(sm[2], sm[3]));
}
DEVI float blk_sum(float v, float* sm){
#pragma unroll
  for (int m = 32; m; m >>= 1) v += __shfl_xor(v, m);
  __syncthreads();
  if ((threadIdx.x & 63) == 0) sm[threadIdx.x >> 6] = v;
  __syncthreads();
  return sm[0] + sm[1] + sm[2] + sm[3];
}

// ---------------- pack kernels ----------------
__global__ void k_pack_whh2(const float* __restrict__ Wf, const float* __restrict__ Wb, u16* __restrict__ out){
  int blk = blockIdx.x;             // 2*1024
  int d = blk >> 10, n = blk & 1023;
  const float* W = d ? Wb : Wf;
  int k = threadIdx.x;
  out[((size_t)d * 1024 + n) * 256 + k] = f2bf(W[(size_t)k * 1024 + n]);
}

__global__ void k_pack_decw(const float* __restrict__ Wih, const float* __restrict__ Whh, ushort4* __restrict__ out){
  int idx = blockIdx.x * 256 + threadIdx.x;      // 768*256
  int k = idx >> 8, j = idx & 255;
  const float* row = (k < 512) ? (Wih + (size_t)(128 + k) * 1024) : (Whh + (size_t)(k - 512) * 1024);
  ushort4 r;
  r.x = f2bf(row[j]);       r.y = f2bf(row[256 + j]);
  r.z = f2bf(row[512 + j]); r.w = f2bf(row[768 + j]);
  out[idx] = r;
}

// vW [768][32000] f32 -> vWt [32000][768] bf16 (transposed for MFMA B frags)
__global__ __launch_bounds__(256) void k_pack_vwt(const float* __restrict__ vW, u16* __restrict__ vWt){
  __shared__ float ts[64][65];
  int nt = blockIdx.x, kt = blockIdx.y;   // 500 x 12
  int tid = threadIdx.x;
#pragma unroll
  for (int i = 0; i < 16; ++i){
    int idx = tid + i * 256;
    int kl = idx >> 6, nl = idx & 63;
    ts[kl][nl] = vW[(size_t)(kt * 64 + kl) * 32000 + nt * 64 + nl];
  }
  __syncthreads();
#pragma unroll
  for (int i = 0; i < 16; ++i){
    int idx = tid + i * 256;
    int nl = idx >> 6, kl = idx & 63;
    vWt[(size_t)(nt * 64 + nl) * 768 + kt * 64 + kl] = f2bf(ts[kl][nl]);
  }
}

// ---------------- encoder ----------------
__global__ __launch_bounds__(256) void k_enc_pre2(const int* __restrict__ src, const float* __restrict__ emb,
                          const float* __restrict__ Wf, const float* __restrict__ bf_,
                          const float* __restrict__ Wb, const float* __restrict__ bb_,
                          u16* __restrict__ xw){
  int d = blockIdx.x / 400, s = blockIdx.x % 400;
  const float* Wih = d ? Wb : Wf; const float* bias = d ? bb_ : bf_;
  __shared__ float es[16][128];
  int tid = threadIdx.x;
  for (int idx = tid; idx < 16 * 128; idx += 256){
    int b = idx >> 7, e = idx & 127;
    es[b][e] = emb[(size_t)src[b * 400 + s] * 128 + e];
  }
  __syncthreads();
  int j = tid;
  float a[4][16];
#pragma unroll
  for (int g = 0; g < 4; ++g){
    float bv = bias[g * 256 + j];
#pragma unroll
    for (int b = 0; b < 16; ++b) a[g][b] = bv;
  }
  for (int e4 = 0; e4 < 32; ++e4){
    float w0[4], w1[4], w2[4], w3[4];
#pragma unroll
    for (int u = 0; u < 4; ++u){
      int e = e4 * 4 + u;
      w0[u] = Wih[(size_t)e * 1024 + j];
      w1[u] = Wih[(size_t)e * 1024 + 256 + j];
      w2[u] = Wih[(size_t)e * 1024 + 512 + j];
      w3[u] = Wih[(size_t)e * 1024 + 768 + j];
    }
#pragma unroll
    for (int b = 0; b < 16; ++b){
      float4 x = *(const float4*)&es[b][e4 * 4];
      a[0][b] += x.x * w0[0] + x.y * w0[1] + x.z * w0[2] + x.w * w0[3];
      a[1][b] += x.x * w1[0] + x.y * w1[1] + x.z * w1[2] + x.w * w1[3];
      a[2][b] += x.x * w2[0] + x.y * w2[1] + x.z * w2[2] + x.w * w2[3];
      a[3][b] += x.x * w3[0] + x.y * w3[1] + x.z * w3[2] + x.w * w3[3];
    }
  }
#pragma unroll
  for (int g = 0; g < 4; ++g){
    u16 tmp[16];
#pragma unroll
    for (int b = 0; b < 16; ++b) tmp[b] = f2bf(a[g][b]);
    uint4* dst = (uint4*)&xw[(((size_t)(d * 400 + s)) * 1024 + g * 256 + j) * 16];
    dst[0] = *(uint4*)&tmp[0];
    dst[1] = *(uint4*)&tmp[8];
  }
}

__global__ __launch_bounds__(512, 2) void k_enc_lstm2(
    const u16* __restrict__ xw, const u16* __restrict__ wpk,
    u16* __restrict__ enc_out, float* __restrict__ hfin, float* __restrict__ cfin)
{
  const int d = blockIdx.x;
  const int tid = threadIdx.x;
  const int w = tid >> 6;
  const int lane = tid & 63;
  const int q = lane & 15, r = lane >> 4;

  __shared__ u16 hhi[16][264];
  __shared__ u16 hlo[16][264];
  for (int idx = tid; idx < 16 * 264; idx += 512){
    hhi[idx / 264][idx % 264] = 0;
    hlo[idx / 264][idx % 264] = 0;
  }

  const u16* wb = wpk + (size_t)d * 1024 * 256;
  int nn[8];
  bf16x8 br0[8], br1[8];
#pragma unroll
  for (int t = 0; t < 8; ++t){
    int ch = t >> 2, g = t & 3;
    nn[t] = g * 256 + w * 32 + ch * 16 + q;
    br0[t] = *(const bf16x8*)&wb[(size_t)nn[t] * 256 + 0 * 32 + r * 8];
    br1[t] = *(const bf16x8*)&wb[(size_t)nn[t] * 256 + 1 * 32 + r * 8];
  }
  float c[8], hl[8];
#pragma unroll
  for (int i = 0; i < 8; ++i){ c[i] = 0.f; hl[i] = 0.f; }
  __syncthreads();

  for (int it = 0; it < 400; ++it){
    int s = d ? (399 - it) : it;
    f32x4 acc[8];
    const u16* xb = xw + ((size_t)(d * 400 + s)) * 1024 * 16;
#pragma unroll
    for (int t = 0; t < 8; ++t){
      ushort4 xv = *(const ushort4*)&xb[nn[t] * 16 + 4 * r];
      f32x4 v;
      v[0] = bf2f(xv.x); v[1] = bf2f(xv.y); v[2] = bf2f(xv.z); v[3] = bf2f(xv.w);
      acc[t] = v;
    }

    bf16x8 sA[8], sB[8];
#define LOADS(BUF, KB) \
    _Pragma("unroll") for (int t = 0; t < 8; ++t) \
      BUF[t] = *(const bf16x8*)&wb[(size_t)nn[t] * 256 + (KB) * 32 + r * 8];

    bf16x8 ahC = *(const bf16x8*)&hhi[q][0 * 32 + r * 8];
    bf16x8 alC = *(const bf16x8*)&hlo[q][0 * 32 + r * 8];
#define MMSTEP(KB, BUF) { \
    bf16x8 ahN, alN; \
    if ((KB) < 7){ ahN = *(const bf16x8*)&hhi[q][((KB)+1) * 32 + r * 8]; \
                   alN = *(const bf16x8*)&hlo[q][((KB)+1) * 32 + r * 8]; } \
    _Pragma("unroll") for (int t = 0; t < 8; ++t){ \
      acc[t] = __builtin_amdgcn_mfma_f32_16x16x32_bf16(ahC, BUF[t], acc[t], 0, 0, 0); \
      acc[t] = __builtin_amdgcn_mfma_f32_16x16x32_bf16(alC, BUF[t], acc[t], 0, 0, 0); } \
    if ((KB) < 7){ ahC = ahN; alC = alN; } }

    LOADS(sA, 2)
    MMSTEP(0, br0)
    MMSTEP(1, br1)
    LOADS(sB, 3)  MMSTEP(2, sA)
    LOADS(sA, 4)  MMSTEP(3, sB)
    LOADS(sB, 5)  MMSTEP(4, sA)
    LOADS(sA, 6)  MMSTEP(5, sB)
    LOADS(sB, 7)  MMSTEP(6, sA)
    MMSTEP(7, sB)
#undef LOADS
#undef MMSTEP

#pragma unroll
    for (int ch = 0; ch < 2; ++ch){
#pragma unroll
      for (int rg = 0; rg < 4; ++rg){
        float pi = acc[ch * 4 + 0][rg], pf = acc[ch * 4 + 1][rg];
        float pg = acc[ch * 4 + 2][rg], po = acc[ch * 4 + 3][rg];
        int ci = ch * 4 + rg;
        float cv = sigm(pf) * c[ci] + sigm(pi) * tanh_f(pg);
        float hv = sigm(po) * tanh_f(cv);
        c[ci] = cv; hl[ci] = hv;
      }
    }
    __syncthreads();
#pragma unroll
    for (int ch = 0; ch < 2; ++ch){
      int hc = w * 32 + ch * 16 + q;
#pragma unroll
      for (int rg = 0; rg < 4; ++rg){
        int b = 4 * r + rg;
        float hv = hl[ch * 4 + rg];
        u16 hi = f2bf(hv);
        float hif = bf2f(hi);
        u16 lo = f2bf(hv - hif);
        hhi[b][hc] = hi; hlo[b][hc] = lo;
        enc_out[((size_t)b * 400 + s) * 512 + d * 256 + hc] = hi;
      }
    }
    __syncthreads();
  }
#pragma unroll
  for (int ch = 0; ch < 2; ++ch){
    int hc = w * 32 + ch * 16 + q;
#pragma unroll
    for (int rg = 0; rg < 4; ++rg){
      int b = 4 * r + rg;
      hfin[(d * 16 + b) * 256 + hc] = hl[ch * 4 + rg];
      cfin[(d * 16 + b) * 256 + hc] = c[ch * 4 + rg];
    }
  }
}

// h0 -> astore slot0 cols 512..767 (stride 768); c0 -> cbuf slot0
__global__ void k_reduce(const float* __restrict__ hfin, const float* __restrict__ cfin,
                         const float* __restrict__ rhW, const float* __restrict__ rhb,
                         const float* __restrict__ rcW, const float* __restrict__ rcb,
                         float* __restrict__ astore0, float* __restrict__ c0){
  int b = blockIdx.x, j = threadIdx.x;
  float ah = rhb[j], ac = rcb[j];
  for (int k = 0; k < 256; ++k){
    float hv = hfin[b * 256 + k], cv = cfin[b * 256 + k];
    ah += hv * rhW[k * 256 + j];
    ac += cv * rcW[k * 256 + j];
  }
  for (int k = 0; k < 256; ++k){
    float hv = hfin[(16 + b) * 256 + k], cv = cfin[(16 + b) * 256 + k];
    ah += hv * rhW[(256 + k) * 256 + j];
    ac += cv * rcW[(256 + k) * 256 + j];
  }
  astore0[b * 768 + 512 + j] = tanh_f(ah);
  c0[b * 256 + j] = tanh_f(ac);
}

__global__ void k_encfeat(const u16* __restrict__ enc_out, const float* __restrict__ Wh, u16* __restrict__ feat){
  int blk = blockIdx.x; int b = blk / 25; int sc = blk % 25;
  int j = threadIdx.x;
  float acc[16];
#pragma unroll
  for (int i = 0; i < 16; ++i) acc[i] = 0.f;
  const u32* ebase = (const u32*)(enc_out + ((size_t)b * 400 + sc * 16) * 512);
  for (int k2 = 0; k2 < 256; ++k2){
    float wa = Wh[(2 * k2) * 256 + j], wb_ = Wh[(2 * k2 + 1) * 256 + j];
#pragma unroll
    for (int ss = 0; ss < 16; ++ss){
      u32 p = ebase[ss * 256 + k2];
      acc[ss] += bf2f((u16)(p & 0xffff)) * wa + bf2f((u16)(p >> 16)) * wb_;
    }
  }
#pragma unroll
  for (int ss = 0; ss < 16; ++ss)
    feat[((size_t)b * 400 + sc * 16 + ss) * 256 + j] = f2bf(acc[ss]);
}

// ---------------- decoder precompute ----------------
__global__ void k_dec_pre(const int* __restrict__ din, const float* __restrict__ emb,
                          const float* __restrict__ Wih, const float* __restrict__ db,
                          const float* __restrict__ pgW,
                          float4* __restrict__ xwd, float* __restrict__ pg_emb){
  int blk = blockIdx.x; int t = blk / 16, b = blk % 16;
  int j = threadIdx.x;
  int id = din[b * 50 + t];
  const float* er = emb + (size_t)id * 128;
  float a0 = db[j], a1 = db[256 + j], a2 = db[512 + j], a3 = db[768 + j];
  for (int e = 0; e < 128; ++e){
    float x = er[e];
    const float* wr = Wih + (size_t)e * 1024;
    a0 += x * wr[j]; a1 += x * wr[256 + j]; a2 += x * wr[512 + j]; a3 += x * wr[768 + j];
  }
  xwd[(size_t)blk * 256 + j] = make_float4(a0, a1, a2, a3);
  __shared__ float red[256];
  float pe = 0.f;
  if (j < 128) pe = er[j] * pgW[768 + j];
  red[j] = pe; __syncthreads();
  for (int off = 128; off; off >>= 1){ if (j < off) red[j] += red[j + off]; __syncthreads(); }
  if (j == 0) pg_emb[blk] = red[0];
}

// ---------------- decoder step kernels ----------------
// ain = astore slot t ([ctx_{t-1}; h_{t-1}] per batch, stride 768)
// hout = astore slot t+1 (h_t written at cols 512..767)
__global__ __launch_bounds__(256) void k_cell(const float* __restrict__ ain,
                                              const float* __restrict__ cin, const ushort4* __restrict__ Wp,
                                              const float4* __restrict__ xwd, int t,
                                              float* __restrict__ hout, float* __restrict__ cout){
  int hcbase = blockIdx.x * 4;
  int tid = threadIdx.x;
  int b = tid & 15, hcl = (tid >> 4) & 3, ks = tid >> 6;
  __shared__ float a_lds[16][772];
  __shared__ float part[4][16][4][4];
  for (int idx = tid; idx < 16 * 768; idx += 256)
    a_lds[idx / 768][idx % 768] = ain[idx];
  __syncthreads();
  int hc = hcbase + hcl;
  float g0 = 0.f, g1 = 0.f, g2 = 0.f, g3 = 0.f;
  const ushort4* wb = Wp + hc;
  const float* arow = a_lds[b];
  for (int k = ks * 192; k < ks * 192 + 192; k += 4){
    float4 av = *(const float4*)(arow + k);
    ushort4 w0 = wb[(k + 0) * 256];
    ushort4 w1 = wb[(k + 1) * 256];
    ushort4 w2 = wb[(k + 2) * 256];
    ushort4 w3 = wb[(k + 3) * 256];
    g0 += av.x * bf2f(w0.x) + av.y * bf2f(w1.x) + av.z * bf2f(w2.x) + av.w * bf2f(w3.x);
    g1 += av.x * bf2f(w0.y) + av.y * bf2f(w1.y) + av.z * bf2f(w2.y) + av.w * bf2f(w3.y);
    g2 += av.x * bf2f(w0.z) + av.y * bf2f(w1.z) + av.z * bf2f(w2.z) + av.w * bf2f(w3.z);
    g3 += av.x * bf2f(w0.w) + av.y * bf2f(w1.w) + av.z * bf2f(w2.w) + av.w * bf2f(w3.w);
  }
  part[ks][b][hcl][0] = g0; part[ks][b][hcl][1] = g1;
  part[ks][b][hcl][2] = g2; part[ks][b][hcl][3] = g3;
  __syncthreads();
  if (tid < 64){
    int b2 = tid & 15, h2 = tid >> 4;
    float4 xv = xwd[((size_t)t * 16 + b2) * 256 + hcbase + h2];
    float s0 = xv.x + part[0][b2][h2][0] + part[1][b2][h2][0] + part[2][b2][h2][0] + part[3][b2][h2][0];
    float s1 = xv.y + part[0][b2][h2][1] + part[1][b2][h2][1] + part[2][b2][h2][1] + part[3][b2][h2][1];
    float s2 = xv.z + part[0][b2][h2][2] + part[1][b2][h2][2] + part[2][b2][h2][2] + part[3][b2][h2][2];
    float s3 = xv.w + part[0][b2][h2][3] + part[1][b2][h2][3] + part[2][b2][h2][3] + part[3][b2][h2][3];
    float iv = sigm(s0), fv = sigm(s1), gv = tanh_f(s2), ov = sigm(s3);
    int hcg = hcbase + h2;
    float cv = fv * cin[b2 * 256 + hcg] + iv * gv;
    float hv = ov * tanh_f(cv);
    cout[b2 * 256 + hcg] = cv;
    hout[b2 * 768 + 512 + hcg] = hv;
  }
}

// aslot1 = astore slot t+1: reads h_t at cols 512.., writes ctx_t at cols 0..511
__global__ __launch_bounds__(256) void k_attn(float* __restrict__ aslot1, const u16* __restrict__ feat,
    const u16* __restrict__ enc_out, const int* __restrict__ src, const int* __restrict__ src_ext,
    const int* __restrict__ tgt_ext, const float* __restrict__ Ws, const float* __restrict__ Wsb,
    const float* __restrict__ Wc, const float* __restrict__ av_, const float* __restrict__ pgW,
    const float* __restrict__ pg_emb, const float* __restrict__ pgb, const float* __restrict__ pgbias,
    float* __restrict__ coverage,
    float* __restrict__ pg_t, float* __restrict__ cvl_t, float* __restrict__ sct_t, int t){
  int b = blockIdx.x; int tid = threadIdx.x;
  __shared__ float hws_s[256];
  __shared__ float sc_s[400];
  __shared__ float at_s[400];
  __shared__ float ctx_s[512];
  __shared__ float red_s[4];
  {
    float acc = Wsb[tid];
    const float* hb_ = aslot1 + b * 768 + 512;
    for (int k = 0; k < 256; ++k) acc += hb_[k] * Ws[k * 256 + tid];
    hws_s[tid] = acc;
  }
  __syncthreads();
  {
    int w = tid >> 6, L = tid & 63;
    float4 hw = *(const float4*)&hws_s[4 * L];
    float4 wc = *(const float4*)&Wc[4 * L];
    float4 vv = *(const float4*)&av_[4 * L];
    for (int s = w; s < 400; s += 4){
      float cv = coverage[b * 400 + s];
      const u16* fp = feat + ((size_t)b * 400 + s) * 256 + 4 * L;
      u32 p0 = *(const u32*)fp; u32 p1 = *(const u32*)(fp + 2);
      float f0 = bf2f((u16)(p0 & 0xffff)) + hw.x + cv * wc.x;
      float f1 = bf2f((u16)(p0 >> 16))    + hw.y + cv * wc.y;
      float f2 = bf2f((u16)(p1 & 0xffff)) + hw.z + cv * wc.z;
      float f3 = bf2f((u16)(p1 >> 16))    + hw.w + cv * wc.w;
      float sc = tanh_f(f0) * vv.x + tanh_f(f1) * vv.y + tanh_f(f2) * vv.z + tanh_f(f3) * vv.w;
#pragma unroll
      for (int m = 32; m; m >>= 1) sc += __shfl_xor(sc, m);
      if (L == 0) sc_s[s] = (src[b * 400 + s] == 0) ? -1e9f : sc;
    }
  }
  __syncthreads();
  {
    float m = -1e30f;
    for (int s = tid; s < 400; s += 256) m = fmaxf(m, sc_s[s]);
    float mx = blk_max(m, red_s);
    float e = 0.f;
    for (int s = tid; s < 400; s += 256){ float ee = __expf(sc_s[s] - mx); at_s[s] = ee; e += ee; }
    float sum = blk_sum(e, red_s);
    float inv = 1.f / sum;
    for (int s = tid; s < 400; s += 256) at_s[s] *= inv;
  }
  __syncthreads();
  {
    float a0 = 0.f, a1 = 0.f;
    const u16* eb = enc_out + (size_t)b * 400 * 512;
    for (int sq = 0; sq < 100; ++sq){
      float4 aq = *(const float4*)&at_s[4 * sq];
      const u16* r0 = eb + (size_t)(4 * sq) * 512;
      a0 += aq.x * bf2f(r0[tid])        + aq.y * bf2f(r0[512 + tid])
          + aq.z * bf2f(r0[1024 + tid]) + aq.w * bf2f(r0[1536 + tid]);
      a1 += aq.x * bf2f(r0[256 + tid])  + aq.y * bf2f(r0[768 + tid])
          + aq.z * bf2f(r0[1280 + tid]) + aq.w * bf2f(r0[1792 + tid]);
    }
    ctx_s[tid] = a0; ctx_s[256 + tid] = a1;
    aslot1[b * 768 + tid] = a0; aslot1[b * 768 + 256 + tid] = a1;
  }
  float clp = 0.f, scp = 0.f;
  {
    int tg = tgt_ext[b * 50 + t];
    for (int s = tid; s < 400; s += 256){
      float a = at_s[s];
      float cv = coverage[b * 400 + s];
      clp += fminf(a, cv);
      coverage[b * 400 + s] = cv + a;
      if (src_ext[b * 400 + s] == tg) scp += a;
    }
  }
  __syncthreads();
  {
    float p = ctx_s[tid] * pgW[tid] + ctx_s[256 + tid] * pgW[256 + tid]
            + aslot1[b * 768 + 512 + tid] * pgW[512 + tid];
    float dsum = blk_sum(p, red_s);
    float cl = blk_sum(clp, red_s);
    float sc2 = blk_sum(scp, red_s);
    if (tid == 0){
      float pg = sigm(dsum + pg_emb[t * 16 + b] + pgb[0] + pgbias[0]);
      pg = fminf(fmaxf(pg, 0.1f), 0.9f);
      pg_t[b] = pg; cvl_t[b] = cl; sct_t[b] = sc2;
    }
  }
}

// ---------------- batched vocab ----------------
// astoreA = astore slot1 base = A[800][768] f32 -> bf16; tgt_row[m]
__global__ void k_pack_a(const float* __restrict__ astoreA, const int* __restrict__ tgt_ext,
                         u16* __restrict__ Abf, int* __restrict__ tgt_row){
  int m = blockIdx.x; int tid = threadIdx.x;
  for (int e = tid; e < 768; e += 256) Abf[(size_t)m * 768 + e] = f2bf(astoreA[(size_t)m * 768 + e]);
  if (tid == 0) tgt_row[m] = tgt_ext[(m & 15) * 50 + (m >> 4)];
}

// logits = A[800][768] @ vW[768][32000]; per-row max/sumexp partials per n-slab + target logit.
// grid: (125 n-slabs, 10 m-slabs of 80 rows); block 256 = 4 waves, wave covers 64 cols.
__global__ __launch_bounds__(256) void k_vgemm(const u16* __restrict__ Abf, const u16* __restrict__ vWt,
    const float* __restrict__ vb, const int* __restrict__ tgt_row,
    float* __restrict__ mpart2, float* __restrict__ spart2, float* __restrict__ ltgt_all){
  int nslab = blockIdx.x, mslab = blockIdx.y;
  int tid = threadIdx.x;
  int w = tid >> 6, lane = tid & 63, q = lane & 15, r = lane >> 4;
  int m0 = mslab * 80;
  int n0w = nslab * 256 + w * 64;
  f32x4 acc[5][4];
#pragma unroll
  for (int mt = 0; mt < 5; ++mt)
#pragma unroll
    for (int nt = 0; nt < 4; ++nt){ acc[mt][nt][0]=0.f; acc[mt][nt][1]=0.f; acc[mt][nt][2]=0.f; acc[mt][nt][3]=0.f; }

  for (int kb = 0; kb < 24; ++kb){
    bf16x8 bfrag[4], afrag[5];
#pragma unroll
    for (int nt = 0; nt < 4; ++nt)
      bfrag[nt] = *(const bf16x8*)&vWt[(size_t)(n0w + nt * 16 + q) * 768 + kb * 32 + r * 8];
#pragma unroll
    for (int mt = 0; mt < 5; ++mt)
      afrag[mt] = *(const bf16x8*)&Abf[(size_t)(m0 + mt * 16 + q) * 768 + kb * 32 + r * 8];
#pragma unroll
    for (int mt = 0; mt < 5; ++mt)
#pragma unroll
      for (int nt = 0; nt < 4; ++nt)
        acc[mt][nt] = __builtin_amdgcn_mfma_f32_16x16x32_bf16(afrag[mt], bfrag[nt], acc[mt][nt], 0, 0, 0);
  }
  float vbc[4];
#pragma unroll
  for (int nt = 0; nt < 4; ++nt) vbc[nt] = vb[n0w + nt * 16 + q];

  __shared__ float pm[4][80], ps[4][80];
#pragma unroll
  for (int mt = 0; mt < 5; ++mt){
#pragma unroll
    for (int rg = 0; rg < 4; ++rg){
      int row = m0 + mt * 16 + 4 * r + rg;
      int tg = tgt_row[row];
      float v0 = acc[mt][0][rg] + vbc[0];
      float v1 = acc[mt][1][rg] + vbc[1];
      float v2 = acc[mt][2][rg] + vbc[2];
      float v3 = acc[mt][3][rg] + vbc[3];
      if (n0w + 0 * 16 + q == tg) ltgt_all[row] = v0;
      if (n0w + 1 * 16 + q == tg) ltgt_all[row] = v1;
      if (n0w + 2 * 16 + q == tg) ltgt_all[row] = v2;
      if (n0w + 3 * 16 + q == tg) ltgt_all[row] = v3;
      float mx = fmaxf(fmaxf(v0, v1), fmaxf(v2, v3));
#pragma unroll
      for (int mk = 1; mk < 16; mk <<= 1) mx = fmaxf(mx, __shfl_xor(mx, mk));
      float se = __expf(v0 - mx) + __expf(v1 - mx) + __expf(v2 - mx) + __expf(v3 - mx);
#pragma unroll
      for (int mk = 1; mk < 16; mk <<= 1) se += __shfl_xor(se, mk);
      if (q == 0){ pm[w][mt * 16 + 4 * r + rg] = mx; ps[w][mt * 16 + 4 * r + rg] = se; }
    }
  }
  __syncthreads();
  if (tid < 80){
    float m = pm[0][tid], s = ps[0][tid];
#pragma unroll
    for (int w2 = 1; w2 < 4; ++w2){
      float om = pm[w2][tid], os = ps[w2][tid];
      float M = fmaxf(m, om);
      s = s * __expf(m - M) + os * __expf(om - M);
      m = M;
    }
    mpart2[(size_t)(m0 + tid) * 125 + nslab] = m;
    spart2[(size_t)(m0 + tid) * 125 + nslab] = s;
  }
}

__global__ void k_comb2(const float* __restrict__ mpart2, const float* __restrict__ spart2,
                        const float* __restrict__ ltgt_all, const float* __restrict__ pg_all,
                        const float* __restrict__ cvl_all, const float* __restrict__ sct_all,
                        const int* __restrict__ tgt_ext, const float* __restrict__ lam,
                        float* __restrict__ loss_g, float* __restrict__ valid_g){
  int t = blockIdx.x; int tid = threadIdx.x;
  int b = tid >> 4, l16 = tid & 15;
  int row = t * 16 + b;
  float m = -1e30f, s = 0.f;
  for (int i = l16; i < 125; i += 16){
    float om = mpart2[(size_t)row * 125 + i], os = spart2[(size_t)row * 125 + i];
    float M = fmaxf(m, om);
    s = s * __expf(m - M) + os * __expf(om - M);
    m = M;
  }
#pragma unroll
  for (int mk = 1; mk < 16; mk <<= 1){
    float om = __shfl_xor(m, mk), os = __shfl_xor(s, mk);
    float M = fmaxf(m, om);
    s = s * __expf(m - M) + os * __expf(om - M);
    m = M;
  }
  if (l16 == 0){
    int tg = tgt_ext[b * 50 + t];
    float pv = (tg < 32000) ? (__expf(ltgt_all[row] - m) / s) : 0.f;
    float pg = pg_all[row];
    float pf = pg * pv + (1.f - pg) * sct_all[row];
    float sl = -__logf(pf + 1e-12f);
    float msk = (tg != 0) ? 1.f : 0.f;
    loss_g[row] = (sl + lam[0] * cvl_all[row]) * msk;
    valid_g[row] = msk;
  }
}

// ---------------- fallback per-step vocab (f32) ----------------
__global__ __launch_bounds__(256) void k_vocab(const float* __restrict__ adec, const float* __restrict__ vW,
    const float* __restrict__ vb, const int* __restrict__ tgt_ext, int t,
    float* __restrict__ mpart, float* __restrict__ spart, float* __restrict__ ltgt){
  int col0 = blockIdx.x * 128;
  int tid = threadIdx.x;
  int cl = tid & 127, half = tid >> 7;
  int col = col0 + cl;
  float acc[16];
#pragma unroll
  for (int i = 0; i < 16; ++i) acc[i] = 0.f;
  const float* Wc = vW + col;
  for (int k = half * 384; k < half * 384 + 384; k += 4){
    float w0 = Wc[(size_t)(k + 0) * 32000];
    float w1 = Wc[(size_t)(k + 1) * 32000];
    float w2 = Wc[(size_t)(k + 2) * 32000];
    float w3 = Wc[(size_t)(k + 3) * 32000];
#pragma unroll
    for (int b = 0; b < 16; ++b){
      const float* Ab = adec + b * 768 + k;
      acc[b] += Ab[0] * w0 + Ab[1] * w1 + Ab[2] * w2 + Ab[3] * w3;
    }
  }
  __shared__ float Ls[2][16][128];
#pragma unroll
  for (int b2 = 0; b2 < 16; ++b2) Ls[half][b2][cl] = acc[b2];
  __syncthreads();
  if (half == 0){
    float vbc = vb[col];
#pragma unroll
    for (int b2 = 0; b2 < 16; ++b2) Ls[0][b2][cl] = Ls[0][b2][cl] + Ls[1][b2][cl] + vbc;
  }
  __syncthreads();
  {
    int b2 = tid >> 4, l16 = tid & 15;
    float m = -1e30f, ssum = 0.f;
#pragma unroll
    for (int i = 0; i < 8; ++i){
      float x = Ls[0][b2][l16 + 16 * i];
      float M = fmaxf(m, x);
      ssum = ssum * __expf(m - M) + __expf(x - M);
      m = M;
    }
#pragma unroll
    for (int mk = 1; mk < 16; mk <<= 1){
      float om = __shfl_xor(m, mk), os = __shfl_xor(ssum, mk);
      float M = fmaxf(m, om);
      ssum = ssum * __expf(m - M) + os * __expf(om - M);
      m = M;
    }
    if (l16 == 0){ mpart[b2 * 250 + blockIdx.x] = m; spart[b2 * 250 + blockIdx.x] = ssum; }
  }
  if (tid < 16){
    int tg = tgt_ext[tid * 50 + t];
    unsigned offc = (unsigned)(tg - col0);
    if (offc < 128u) ltgt[tid] = Ls[0][tid][offc];
  }
}

__global__ void k_comb(const float* __restrict__ mpart, const float* __restrict__ spart,
                       const float* __restrict__ ltgt, const float* __restrict__ pg_g,
                       const float* __restrict__ cvl_g, const float* __restrict__ sct_g,
                       const int* __restrict__ tgt_ext, const float* __restrict__ lam, int t,
                       float* __restrict__ loss_g, float* __restrict__ valid_g){
  int tid = threadIdx.x;
  int b = tid >> 4, l16 = tid & 15;
  float m = -1e30f, s = 0.f;
  for (int i = l16; i < 250; i += 16){
    float om = mpart[b * 250 + i], os = spart[b * 250 + i];
    float M = fmaxf(m, om);
    s = s * __expf(m - M) + os * __expf(om - M);
    m = M;
  }
#pragma unroll
  for (int mk = 1; mk < 16; mk <<= 1){
    float om = __shfl_xor(m, mk), os = __shfl_xor(s, mk);
    float M = fmaxf(m, om);
    s = s * __expf(m - M) + os * __expf(om - M);
    m = M;
  }
  if (l16 == 0){
    int tg = tgt_ext[b * 50 + t];
    float pv = (tg < 32000) ? (__expf(ltgt[b] - m) / s) : 0.f;
    float pg = pg_g[b];
    float pf = pg * pv + (1.f - pg) * sct_g[b];
    float sl = -__logf(pf + 1e-12f);
    float msk = (tg != 0) ? 1.f : 0.f;
    loss_g[t * 16 + b] = (sl + lam[0] * cvl_g[b]) * msk;
    valid_g[t * 16 + b] = msk;
  }
}

__global__ void k_final(const float* __restrict__ loss_g, const float* __restrict__ valid_g, float* __restrict__ out){
  __shared__ float r1[256], r2[256];
  int tid = threadIdx.x;
  float a = 0.f, v = 0.f;
  for (int i = tid; i < 800; i += 256){ a += loss_g[i]; v += valid_g[i]; }
  r1[tid] = a; r2[tid] = v; __syncthreads();
  for (int off = 128; off; off >>= 1){
    if (tid < off){ r1[tid] += r1[tid + off]; r2[tid] += r2[tid + off]; }
    __syncthreads();
  }
  if (tid == 0) out[0] = r1[0] / fmaxf(r2[0], 1.f);
}

extern "C" void kernel_launch(void* const* d_in, const int* in_sizes, int n_in,
                              void* d_out, int out_size, void* d_ws, size_t ws_size,
                              hipStream_t stream){
  const int*   src     = (const int*)  d_in[0];
  const int*   src_ext = (const int*)  d_in[1];
  const int*   dec_in  = (const int*)  d_in[2];
  const int*   tgt_ext = (const int*)  d_in[3];
  const float* enc_emb = (const float*)d_in[5];
  const float* eWihF   = (const float*)d_in[6];
  const float* eWhhF   = (const float*)d_in[7];
  const float* ebF     = (const float*)d_in[8];
  const float* eWihB   = (const float*)d_in[9];
  const float* eWhhB   = (const float*)d_in[10];
  const float* ebB     = (const float*)d_in[11];
  const float* rhW     = (const float*)d_in[12];
  const float* rhb     = (const float*)d_in[13];
  const float* rcW     = (const float*)d_in[14];
  const float* rcb     = (const float*)d_in[15];
  const float* dec_emb = (const float*)d_in[16];
  const float* dWih    = (const float*)d_in[17];
  const float* dWhh    = (const float*)d_in[18];
  const float* db_     = (const float*)d_in[19];
  const float* aWh     = (const float*)d_in[20];
  const float* aWs     = (const float*)d_in[21];
  const float* aWsb    = (const float*)d_in[22];
  const float* aWc     = (const float*)d_in[23];
  const float* av      = (const float*)d_in[24];
  const float* pgW     = (const float*)d_in[25];
  const float* pgb     = (const float*)d_in[26];
  const float* vW      = (const float*)d_in[27];
  const float* vb      = (const float*)d_in[28];
  const float* lam     = (const float*)d_in[29];
  const float* pgbias  = (const float*)d_in[30];
  (void)in_sizes; (void)n_in; (void)out_size;

  char* w = (char*)d_ws;
  size_t off = 0;
  auto alloc = [&](size_t bytes) -> char* {
    char* p = w + off; off += (bytes + 255) & ~(size_t)255; return p;
  };
  u16*     xw      = (u16*)    alloc(2ull * 400 * 1024 * 16 * 2);
  u16*     whhp    = (u16*)    alloc(2ull * 1024 * 256 * 2);
  ushort4* decwp   = (ushort4*)alloc(768ull * 256 * 8);
  u16*     enc_out = (u16*)    alloc(16ull * 400 * 512 * 2);
  u16*     feat    = (u16*)    alloc(16ull * 400 * 256 * 2);
  float*   hfin    = (float*)  alloc(2 * 16 * 256 * 4);
  float*   cfin    = (float*)  alloc(2 * 16 * 256 * 4);
  float*   cbuf    = (float*)  alloc(2 * 16 * 256 * 4);
  float4*  xwd     = (float4*) alloc(50ull * 16 * 256 * 16);
  float*   pg_emb  = (float*)  alloc(800 * 4);
  float*   coverage= (float*)  alloc(16 * 400 * 4);        // 25600 (aligned)
  float*   astore  = (float*)  alloc(51ull * 16 * 768 * 4); // contiguous after coverage
  float*   mpartF  = (float*)  alloc(16 * 250 * 4);
  float*   spartF  = (float*)  alloc(16 * 250 * 4);
  float*   ltgt_all= (float*)  alloc(800 * 4);
  float*   pg_all  = (float*)  alloc(800 * 4);
  float*   cvl_all = (float*)  alloc(800 * 4);
  float*   sct_all = (float*)  alloc(800 * 4);
  float*   loss_g  = (float*)  alloc(800 * 4);
  float*   valid_g = (float*)  alloc(800 * 4);
  int*     tgt_row = (int*)    alloc(800 * 4);
  // batched-vocab extras at the end so the fallback path never needs them
  float*   mpart2  = (float*)  alloc(800ull * 125 * 4);
  float*   spart2  = (float*)  alloc(800ull * 125 * 4);
  u16*     Abf     = (u16*)    alloc(800ull * 768 * 2);
  u16*     vWt     = (u16*)    alloc(32000ull * 768 * 2);
  bool use_batched = (off <= ws_size);

  // zero coverage + astore slot0 (contiguous: 25600 + 49152 bytes)
  hipMemsetAsync(coverage, 0, 16 * 400 * 4 + 16 * 768 * 4, stream);

  hipLaunchKernelGGL(k_pack_whh2, dim3(2048),  dim3(256), 0, stream, eWhhF, eWhhB, whhp);
  hipLaunchKernelGGL(k_pack_decw, dim3(768),   dim3(256), 0, stream, dWih, dWhh, decwp);
  if (use_batched)
    hipLaunchKernelGGL(k_pack_vwt, dim3(500, 12), dim3(256), 0, stream, vW, vWt);
  hipLaunchKernelGGL(k_enc_pre2,  dim3(800),   dim3(256), 0, stream, src, enc_emb, eWihF, ebF, eWihB, ebB, xw);
  hipLaunchKernelGGL(k_dec_pre,   dim3(800),   dim3(256), 0, stream, dec_in, dec_emb, dWih, db_, pgW, xwd, pg_emb);
  hipLaunchKernelGGL(k_enc_lstm2, dim3(2),     dim3(512), 0, stream, xw, whhp, enc_out, hfin, cfin);
  hipLaunchKernelGGL(k_reduce,    dim3(16),    dim3(256), 0, stream, hfin, cfin, rhW, rhb, rcW, rcb, astore, cbuf);
  hipLaunchKernelGGL(k_encfeat,   dim3(400),   dim3(256), 0, stream, enc_out, aWh, feat);

  for (int t = 0; t < 50; ++t){
    float* aslot0 = astore + (size_t)t * 16 * 768;
    float* aslot1 = astore + (size_t)(t + 1) * 16 * 768;
    float* cin  = cbuf + (t & 1) * 16 * 256;
    float* cout = cbuf + ((t + 1) & 1) * 16 * 256;
    hipLaunchKernelGGL(k_cell,  dim3(64),  dim3(256), 0, stream, aslot0, cin, decwp, xwd, t, aslot1, cout);
    hipLaunchKernelGGL(k_attn,  dim3(16),  dim3(256), 0, stream, aslot1, feat, enc_out, src, src_ext, tgt_ext,
                       aWs, aWsb, aWc, av, pgW, pg_emb, pgb, pgbias, coverage,
                       pg_all + t * 16, cvl_all + t * 16, sct_all + t * 16, t);
    if (!use_batched){
      hipLaunchKernelGGL(k_vocab, dim3(250), dim3(256), 0, stream, aslot1, vW, vb, tgt_ext, t, mpartF, spartF, ltgt_all + t * 16);
      hipLaunchKernelGGL(k_comb,  dim3(1),   dim3(256), 0, stream, mpartF, spartF, ltgt_all + t * 16,
                         pg_all + t * 16, cvl_all + t * 16, sct_all + t * 16, tgt_ext, lam, t, loss_g, valid_g);
    }
  }
  if (use_batched){
    hipLaunchKernelGGL(k_pack_a, dim3(800), dim3(256), 0, stream, astore + 16 * 768, tgt_ext, Abf, tgt_row);
    hipLaunchKernelGGL(k_vgemm,  dim3(125, 10), dim3(256), 0, stream, Abf, vWt, vb, tgt_row, mpart2, spart2, ltgt_all);
    hipLaunchKernelGGL(k_comb2,  dim3(50), dim3(256), 0, stream, mpart2, spart2, ltgt_all,
                       pg_all, cvl_all, sct_all, tgt_ext, lam, loss_g, valid_g);
  }
  hipLaunchKernelGGL(k_final, dim3(1), dim3(256), 0, stream, loss_g, valid_g, (float*)d_out);
}

// Round 4
// 7572.243 us; speedup vs baseline: 2.0138x; 1.1194x over previous
//
#include <hip/hip_runtime.h>
#include <math.h>

typedef unsigned short u16;
typedef unsigned int   u32;
typedef __attribute__((ext_vector_type(8))) short bf16x8;
typedef __attribute__((ext_vector_type(4))) float f32x4;

#define DEVI static __device__ __forceinline__

DEVI float bf2f(u16 u){ u32 x = ((u32)u) << 16; float f; __builtin_memcpy(&f, &x, 4); return f; }
DEVI u16 f2bf(float f){ u32 x; __builtin_memcpy(&x, &f, 4); u32 r = (x + 0x7fffu + ((x >> 16) & 1u)) >> 16; return (u16)r; }
DEVI float sigm(float x){ return 1.f / (1.f + __expf(-x)); }
DEVI float tanh_f(float x){ float e = __expf(2.f * x); return 1.f - 2.f / (e + 1.f); }

DEVI float blk_max(float v, float* sm){
#pragma unroll
  for (int m = 32; m; m >>= 1) v = fmaxf(v, __shfl_xor(v, m));
  __syncthreads();
  if ((threadIdx.x & 63) == 0) sm[threadIdx.x >> 6] = v;
  __syncthreads();
  return fmaxf(fmaxf(sm[0], sm[1]), fmaxf(sm[2], sm[3]));
}
DEVI float blk_sum(float v, float* sm){
#pragma unroll
  for (int m = 32; m; m >>= 1) v += __shfl_xor(v, m);
  __syncthreads();
  if ((threadIdx.x & 63) == 0) sm[threadIdx.x >> 6] = v;
  __syncthreads();
  return sm[0] + sm[1] + sm[2] + sm[3];
}

// ---------------- pack kernels ----------------
__global__ void k_pack_whh2(const float* __restrict__ Wf, const float* __restrict__ Wb, u16* __restrict__ out){
  int blk = blockIdx.x;             // 2*1024
  int d = blk >> 10, n = blk & 1023;
  const float* W = d ? Wb : Wf;
  int k = threadIdx.x;
  out[((size_t)d * 1024 + n) * 256 + k] = f2bf(W[(size_t)k * 1024 + n]);
}

__global__ void k_pack_decw(const float* __restrict__ Wih, const float* __restrict__ Whh, ushort4* __restrict__ out){
  int idx = blockIdx.x * 256 + threadIdx.x;      // 768*256
  int k = idx >> 8, j = idx & 255;
  const float* row = (k < 512) ? (Wih + (size_t)(128 + k) * 1024) : (Whh + (size_t)(k - 512) * 1024);
  ushort4 r;
  r.x = f2bf(row[j]);       r.y = f2bf(row[256 + j]);
  r.z = f2bf(row[512 + j]); r.w = f2bf(row[768 + j]);
  out[idx] = r;
}

// vW [768][32000] f32 -> vWt [32000][768] bf16 (transposed for MFMA B frags)
__global__ __launch_bounds__(256) void k_pack_vwt(const float* __restrict__ vW, u16* __restrict__ vWt){
  __shared__ float ts[64][65];
  int nt = blockIdx.x, kt = blockIdx.y;   // 500 x 12
  int tid = threadIdx.x;
#pragma unroll
  for (int i = 0; i < 16; ++i){
    int idx = tid + i * 256;
    int kl = idx >> 6, nl = idx & 63;
    ts[kl][nl] = vW[(size_t)(kt * 64 + kl) * 32000 + nt * 64 + nl];
  }
  __syncthreads();
#pragma unroll
  for (int i = 0; i < 16; ++i){
    int idx = tid + i * 256;
    int nl = idx >> 6, kl = idx & 63;
    vWt[(size_t)(nt * 64 + nl) * 768 + kt * 64 + kl] = f2bf(ts[kl][nl]);
  }
}

// ---------------- encoder ----------------
// xw[d][s][n][b] bf16 of emb@Wih + bias   (n = gate*256 + hc)
__global__ __launch_bounds__(256) void k_enc_pre2(const int* __restrict__ src, const float* __restrict__ emb,
                          const float* __restrict__ Wf, const float* __restrict__ bf_,
                          const float* __restrict__ Wb, const float* __restrict__ bb_,
                          u16* __restrict__ xw){
  int d = blockIdx.x / 400, s = blockIdx.x % 400;
  const float* Wih = d ? Wb : Wf; const float* bias = d ? bb_ : bf_;
  __shared__ float es[16][128];
  int tid = threadIdx.x;
  for (int idx = tid; idx < 16 * 128; idx += 256){
    int b = idx >> 7, e = idx & 127;
    es[b][e] = emb[(size_t)src[b * 400 + s] * 128 + e];
  }
  __syncthreads();
  int j = tid;
  float a[4][16];
#pragma unroll
  for (int g = 0; g < 4; ++g){
    float bv = bias[g * 256 + j];
#pragma unroll
    for (int b = 0; b < 16; ++b) a[g][b] = bv;
  }
  for (int e4 = 0; e4 < 32; ++e4){
    float w0[4], w1[4], w2[4], w3[4];
#pragma unroll
    for (int u = 0; u < 4; ++u){
      int e = e4 * 4 + u;
      w0[u] = Wih[(size_t)e * 1024 + j];
      w1[u] = Wih[(size_t)e * 1024 + 256 + j];
      w2[u] = Wih[(size_t)e * 1024 + 512 + j];
      w3[u] = Wih[(size_t)e * 1024 + 768 + j];
    }
#pragma unroll
    for (int b = 0; b < 16; ++b){
      float4 x = *(const float4*)&es[b][e4 * 4];
      a[0][b] += x.x * w0[0] + x.y * w0[1] + x.z * w0[2] + x.w * w0[3];
      a[1][b] += x.x * w1[0] + x.y * w1[1] + x.z * w1[2] + x.w * w1[3];
      a[2][b] += x.x * w2[0] + x.y * w2[1] + x.z * w2[2] + x.w * w2[3];
      a[3][b] += x.x * w3[0] + x.y * w3[1] + x.z * w3[2] + x.w * w3[3];
    }
  }
#pragma unroll
  for (int g = 0; g < 4; ++g){
    u16 tmp[16];
#pragma unroll
    for (int b = 0; b < 16; ++b) tmp[b] = f2bf(a[g][b]);
    uint4* dst = (uint4*)&xw[(((size_t)(d * 400 + s)) * 1024 + g * 256 + j) * 16];
    dst[0] = *(uint4*)&tmp[0];
    dst[1] = *(uint4*)&tmp[8];
  }
}

// Persistent multi-block encoder LSTM: 16 blocks (2 dir x 8 hc-groups), 256 thr (4 waves).
// Wave w = gate w; block owns hc in [g*32, g*32+32). Whh slice in registers.
// h exchanged per step as packed (hi<<16|lo) bf16 u32 via agent-scope atomics; one
// monotonic spin barrier per step per direction; hxch double-buffered by step parity.
__global__ __launch_bounds__(256, 1) void k_enc_lstm3(
    const u16* __restrict__ xw, const u16* __restrict__ wpk,
    u16* __restrict__ enc_out, float* __restrict__ hfin, float* __restrict__ cfin,
    u32* __restrict__ hxch, u32* __restrict__ bar)
{
  const int blk = blockIdx.x;
  const int d = blk >> 3, g = blk & 7;
  const int tid = threadIdx.x;
  const int w = tid >> 6, lane = tid & 63;
  const int q = lane & 15, r = lane >> 4;

  __shared__ u16 hhi[16][264];
  __shared__ u16 hlo[16][264];
  __shared__ float gex[4][16][33];
  for (int idx = tid; idx < 16 * 264; idx += 256){
    hhi[idx / 264][idx % 264] = 0;
    hlo[idx / 264][idx % 264] = 0;
  }

  // register-resident Whh slice: 2 n-tiles x 8 k-blocks
  const u16* wb = wpk + (size_t)d * 1024 * 256;
  const int n0 = w * 256 + g * 32 + q;
  bf16x8 wreg[2][8];
#pragma unroll
  for (int half = 0; half < 2; ++half)
#pragma unroll
    for (int kb = 0; kb < 8; ++kb)
      wreg[half][kb] = *(const bf16x8*)&wb[(size_t)(n0 + half * 16) * 256 + kb * 32 + r * 8];

  // combine-phase cell ownership: cells ci = tid and tid+256; ci -> b=ci>>5, hcl=ci&31
  const int b0 = tid >> 5, hcl = tid & 31;
  const int b1 = 8 + b0;
  float c0 = 0.f, c1 = 0.f, h0r = 0.f, h1r = 0.f;

  u32* barp = bar + d * 64;

  // prefetch x(it=0)
  int s = d ? 399 : 0;
  ushort4 xv0 = *(const ushort4*)&xw[((((size_t)(d * 400 + s)) * 1024 + n0) * 16) + 4 * r];
  ushort4 xv1 = *(const ushort4*)&xw[((((size_t)(d * 400 + s)) * 1024 + n0 + 16) * 16) + 4 * r];
  __syncthreads();

  for (int it = 0; it < 400; ++it){
    s = d ? (399 - it) : it;
    // phase 1: MFMA  acc[half] = x + Whh_slice @ h
    f32x4 acc[2];
    acc[0][0] = bf2f(xv0.x); acc[0][1] = bf2f(xv0.y); acc[0][2] = bf2f(xv0.z); acc[0][3] = bf2f(xv0.w);
    acc[1][0] = bf2f(xv1.x); acc[1][1] = bf2f(xv1.y); acc[1][2] = bf2f(xv1.z); acc[1][3] = bf2f(xv1.w);
#pragma unroll
    for (int kb = 0; kb < 8; ++kb){
      bf16x8 ah = *(const bf16x8*)&hhi[q][kb * 32 + r * 8];
      bf16x8 al = *(const bf16x8*)&hlo[q][kb * 32 + r * 8];
      acc[0] = __builtin_amdgcn_mfma_f32_16x16x32_bf16(ah, wreg[0][kb], acc[0], 0, 0, 0);
      acc[0] = __builtin_amdgcn_mfma_f32_16x16x32_bf16(al, wreg[0][kb], acc[0], 0, 0, 0);
      acc[1] = __builtin_amdgcn_mfma_f32_16x16x32_bf16(ah, wreg[1][kb], acc[1], 0, 0, 0);
      acc[1] = __builtin_amdgcn_mfma_f32_16x16x32_bf16(al, wreg[1][kb], acc[1], 0, 0, 0);
    }
    // gate exchange: wave w = gate w; value (b=4r+rg, hcl=half*16+q)
#pragma unroll
    for (int half = 0; half < 2; ++half)
#pragma unroll
      for (int rg = 0; rg < 4; ++rg)
        gex[w][4 * r + rg][half * 16 + q] = acc[half][rg];
    __syncthreads();

    // combine: 2 cells per thread
    {
      float gi = gex[0][b0][hcl], gf = gex[1][b0][hcl], gg = gex[2][b0][hcl], go = gex[3][b0][hcl];
      c0 = sigm(gf) * c0 + sigm(gi) * tanh_f(gg);
      h0r = sigm(go) * tanh_f(c0);
      gi = gex[0][b1][hcl]; gf = gex[1][b1][hcl]; gg = gex[2][b1][hcl]; go = gex[3][b1][hcl];
      c1 = sigm(gf) * c1 + sigm(gi) * tanh_f(gg);
      h1r = sigm(go) * tanh_f(c1);
    }
    // publish h slice (packed hi/lo) + enc_out
    int hb = (it + 1) & 1;
    u32* hx_w = hxch + ((size_t)(hb * 2 + d)) * 16 * 256;
    {
      u16 hi0 = f2bf(h0r); u16 lo0 = f2bf(h0r - bf2f(hi0));
      u16 hi1 = f2bf(h1r); u16 lo1 = f2bf(h1r - bf2f(hi1));
      int hcg = g * 32 + hcl;
      __hip_atomic_store(&hx_w[b0 * 256 + hcg], ((u32)hi0 << 16) | lo0, __ATOMIC_RELAXED, __HIP_MEMORY_SCOPE_AGENT);
      __hip_atomic_store(&hx_w[b1 * 256 + hcg], ((u32)hi1 << 16) | lo1, __ATOMIC_RELAXED, __HIP_MEMORY_SCOPE_AGENT);
      enc_out[((size_t)b0 * 400 + s) * 512 + d * 256 + hcg] = hi0;
      enc_out[((size_t)b1 * 400 + s) * 512 + d * 256 + hcg] = hi1;
    }
    if (it < 399){
      // prefetch next x while waiting
      int sn = d ? (399 - (it + 1)) : (it + 1);
      xv0 = *(const ushort4*)&xw[((((size_t)(d * 400 + sn)) * 1024 + n0) * 16) + 4 * r];
      xv1 = *(const ushort4*)&xw[((((size_t)(d * 400 + sn)) * 1024 + n0 + 16) * 16) + 4 * r];
      __threadfence();
      __syncthreads();
      if (tid == 0){
        __hip_atomic_fetch_add(barp, 1u, __ATOMIC_RELEASE, __HIP_MEMORY_SCOPE_AGENT);
        u32 target = 8u * (u32)(it + 1);
        while (__hip_atomic_load(barp, __ATOMIC_ACQUIRE, __HIP_MEMORY_SCOPE_AGENT) < target)
          __builtin_amdgcn_s_sleep(1);
      }
      __syncthreads();
      // read full h(it+1)
      const u32* hx_r = hxch + ((size_t)(hb * 2 + d)) * 16 * 256;
#pragma unroll
      for (int i = 0; i < 16; ++i){
        u32 p = __hip_atomic_load(&hx_r[i * 256 + tid], __ATOMIC_RELAXED, __HIP_MEMORY_SCOPE_AGENT);
        hhi[i][tid] = (u16)(p >> 16);
        hlo[i][tid] = (u16)(p & 0xffffu);
      }
      __syncthreads();
    }
  }
  {
    int hcg = g * 32 + hcl;
    hfin[(d * 16 + b0) * 256 + hcg] = h0r;
    cfin[(d * 16 + b0) * 256 + hcg] = c0;
    hfin[(d * 16 + b1) * 256 + hcg] = h1r;
    cfin[(d * 16 + b1) * 256 + hcg] = c1;
  }
}

// h0 -> astore slot0 cols 512..767 (stride 768); c0 -> cbuf slot0
__global__ void k_reduce(const float* __restrict__ hfin, const float* __restrict__ cfin,
                         const float* __restrict__ rhW, const float* __restrict__ rhb,
                         const float* __restrict__ rcW, const float* __restrict__ rcb,
                         float* __restrict__ astore0, float* __restrict__ c0){
  int b = blockIdx.x, j = threadIdx.x;
  float ah = rhb[j], ac = rcb[j];
  for (int k = 0; k < 256; ++k){
    float hv = hfin[b * 256 + k], cv = cfin[b * 256 + k];
    ah += hv * rhW[k * 256 + j];
    ac += cv * rcW[k * 256 + j];
  }
  for (int k = 0; k < 256; ++k){
    float hv = hfin[(16 + b) * 256 + k], cv = cfin[(16 + b) * 256 + k];
    ah += hv * rhW[(256 + k) * 256 + j];
    ac += cv * rcW[(256 + k) * 256 + j];
  }
  astore0[b * 768 + 512 + j] = tanh_f(ah);
  c0[b * 256 + j] = tanh_f(ac);
}

__global__ void k_encfeat(const u16* __restrict__ enc_out, const float* __restrict__ Wh, u16* __restrict__ feat){
  int blk = blockIdx.x; int b = blk / 25; int sc = blk % 25;
  int j = threadIdx.x;
  float acc[16];
#pragma unroll
  for (int i = 0; i < 16; ++i) acc[i] = 0.f;
  const u32* ebase = (const u32*)(enc_out + ((size_t)b * 400 + sc * 16) * 512);
  for (int k2 = 0; k2 < 256; ++k2){
    float wa = Wh[(2 * k2) * 256 + j], wb_ = Wh[(2 * k2 + 1) * 256 + j];
#pragma unroll
    for (int ss = 0; ss < 16; ++ss){
      u32 p = ebase[ss * 256 + k2];
      acc[ss] += bf2f((u16)(p & 0xffff)) * wa + bf2f((u16)(p >> 16)) * wb_;
    }
  }
#pragma unroll
  for (int ss = 0; ss < 16; ++ss)
    feat[((size_t)b * 400 + sc * 16 + ss) * 256 + j] = f2bf(acc[ss]);
}

// ---------------- decoder precompute ----------------
__global__ void k_dec_pre(const int* __restrict__ din, const float* __restrict__ emb,
                          const float* __restrict__ Wih, const float* __restrict__ db,
                          const float* __restrict__ pgW,
                          float4* __restrict__ xwd, float* __restrict__ pg_emb){
  int blk = blockIdx.x; int t = blk / 16, b = blk % 16;
  int j = threadIdx.x;
  int id = din[b * 50 + t];
  const float* er = emb + (size_t)id * 128;
  float a0 = db[j], a1 = db[256 + j], a2 = db[512 + j], a3 = db[768 + j];
  for (int e = 0; e < 128; ++e){
    float x = er[e];
    const float* wr = Wih + (size_t)e * 1024;
    a0 += x * wr[j]; a1 += x * wr[256 + j]; a2 += x * wr[512 + j]; a3 += x * wr[768 + j];
  }
  xwd[(size_t)blk * 256 + j] = make_float4(a0, a1, a2, a3);
  __shared__ float red[256];
  float pe = 0.f;
  if (j < 128) pe = er[j] * pgW[768 + j];
  red[j] = pe; __syncthreads();
  for (int off = 128; off; off >>= 1){ if (j < off) red[j] += red[j + off]; __syncthreads(); }
  if (j == 0) pg_emb[blk] = red[0];
}

// ---------------- decoder step kernels ----------------
__global__ __launch_bounds__(256) void k_cell(const float* __restrict__ ain,
                                              const float* __restrict__ cin, const ushort4* __restrict__ Wp,
                                              const float4* __restrict__ xwd, int t,
                                              float* __restrict__ hout, float* __restrict__ cout,
                                              u16* __restrict__ Abf){
  int hcbase = blockIdx.x * 4;
  int tid = threadIdx.x;
  int b = tid & 15, hcl = (tid >> 4) & 3, ks = tid >> 6;
  __shared__ float a_lds[16][772];
  __shared__ float part[4][16][4][4];
  for (int idx = tid; idx < 16 * 768; idx += 256)
    a_lds[idx / 768][idx % 768] = ain[idx];
  __syncthreads();
  int hc = hcbase + hcl;
  float g0 = 0.f, g1 = 0.f, g2 = 0.f, g3 = 0.f;
  const ushort4* wb = Wp + hc;
  const float* arow = a_lds[b];
  for (int k = ks * 192; k < ks * 192 + 192; k += 4){
    float4 av = *(const float4*)(arow + k);
    ushort4 w0 = wb[(k + 0) * 256];
    ushort4 w1 = wb[(k + 1) * 256];
    ushort4 w2 = wb[(k + 2) * 256];
    ushort4 w3 = wb[(k + 3) * 256];
    g0 += av.x * bf2f(w0.x) + av.y * bf2f(w1.x) + av.z * bf2f(w2.x) + av.w * bf2f(w3.x);
    g1 += av.x * bf2f(w0.y) + av.y * bf2f(w1.y) + av.z * bf2f(w2.y) + av.w * bf2f(w3.y);
    g2 += av.x * bf2f(w0.z) + av.y * bf2f(w1.z) + av.z * bf2f(w2.z) + av.w * bf2f(w3.z);
    g3 += av.x * bf2f(w0.w) + av.y * bf2f(w1.w) + av.z * bf2f(w2.w) + av.w * bf2f(w3.w);
  }
  part[ks][b][hcl][0] = g0; part[ks][b][hcl][1] = g1;
  part[ks][b][hcl][2] = g2; part[ks][b][hcl][3] = g3;
  __syncthreads();
  if (tid < 64){
    int b2 = tid & 15, h2 = tid >> 4;
    float4 xv = xwd[((size_t)t * 16 + b2) * 256 + hcbase + h2];
    float s0 = xv.x + part[0][b2][h2][0] + part[1][b2][h2][0] + part[2][b2][h2][0] + part[3][b2][h2][0];
    float s1 = xv.y + part[0][b2][h2][1] + part[1][b2][h2][1] + part[2][b2][h2][1] + part[3][b2][h2][1];
    float s2 = xv.z + part[0][b2][h2][2] + part[1][b2][h2][2] + part[2][b2][h2][2] + part[3][b2][h2][2];
    float s3 = xv.w + part[0][b2][h2][3] + part[1][b2][h2][3] + part[2][b2][h2][3] + part[3][b2][h2][3];
    float iv = sigm(s0), fv = sigm(s1), gv = tanh_f(s2), ov = sigm(s3);
    int hcg = hcbase + h2;
    float cv = fv * cin[b2 * 256 + hcg] + iv * gv;
    float hv = ov * tanh_f(cv);
    cout[b2 * 256 + hcg] = cv;
    hout[b2 * 768 + 512 + hcg] = hv;
    Abf[((size_t)t * 16 + b2) * 768 + 512 + hcg] = f2bf(hv);
  }
}

__global__ __launch_bounds__(256) void k_attn(float* __restrict__ aslot1, const u16* __restrict__ feat,
    const u16* __restrict__ enc_out, const int* __restrict__ src, const int* __restrict__ src_ext,
    const int* __restrict__ tgt_ext, const float* __restrict__ Ws, const float* __restrict__ Wsb,
    const float* __restrict__ Wc, const float* __restrict__ av_, const float* __restrict__ pgW,
    const float* __restrict__ pg_emb, const float* __restrict__ pgb, const float* __restrict__ pgbias,
    float* __restrict__ coverage, u16* __restrict__ Abf,
    float* __restrict__ pg_t, float* __restrict__ cvl_t, float* __restrict__ sct_t, int t){
  int b = blockIdx.x; int tid = threadIdx.x;
  __shared__ float hws_s[256];
  __shared__ float sc_s[400];
  __shared__ float at_s[400];
  __shared__ float ctx_s[512];
  __shared__ float red_s[4];
  {
    float acc = Wsb[tid];
    const float* hb_ = aslot1 + b * 768 + 512;
    for (int k = 0; k < 256; ++k) acc += hb_[k] * Ws[k * 256 + tid];
    hws_s[tid] = acc;
  }
  __syncthreads();
  {
    int w = tid >> 6, L = tid & 63;
    float4 hw = *(const float4*)&hws_s[4 * L];
    float4 wc = *(const float4*)&Wc[4 * L];
    float4 vv = *(const float4*)&av_[4 * L];
    for (int s = w; s < 400; s += 4){
      float cv = coverage[b * 400 + s];
      const u16* fp = feat + ((size_t)b * 400 + s) * 256 + 4 * L;
      u32 p0 = *(const u32*)fp; u32 p1 = *(const u32*)(fp + 2);
      float f0 = bf2f((u16)(p0 & 0xffff)) + hw.x + cv * wc.x;
      float f1 = bf2f((u16)(p0 >> 16))    + hw.y + cv * wc.y;
      float f2 = bf2f((u16)(p1 & 0xffff)) + hw.z + cv * wc.z;
      float f3 = bf2f((u16)(p1 >> 16))    + hw.w + cv * wc.w;
      float sc = tanh_f(f0) * vv.x + tanh_f(f1) * vv.y + tanh_f(f2) * vv.z + tanh_f(f3) * vv.w;
#pragma unroll
      for (int m = 32; m; m >>= 1) sc += __shfl_xor(sc, m);
      if (L == 0) sc_s[s] = (src[b * 400 + s] == 0) ? -1e9f : sc;
    }
  }
  __syncthreads();
  {
    float m = -1e30f;
    for (int s = tid; s < 400; s += 256) m = fmaxf(m, sc_s[s]);
    float mx = blk_max(m, red_s);
    float e = 0.f;
    for (int s = tid; s < 400; s += 256){ float ee = __expf(sc_s[s] - mx); at_s[s] = ee; e += ee; }
    float sum = blk_sum(e, red_s);
    float inv = 1.f / sum;
    for (int s = tid; s < 400; s += 256) at_s[s] *= inv;
  }
  __syncthreads();
  {
    float a0 = 0.f, a1 = 0.f;
    const u16* eb = enc_out + (size_t)b * 400 * 512;
    for (int sq = 0; sq < 100; ++sq){
      float4 aq = *(const float4*)&at_s[4 * sq];
      const u16* r0 = eb + (size_t)(4 * sq) * 512;
      a0 += aq.x * bf2f(r0[tid])        + aq.y * bf2f(r0[512 + tid])
          + aq.z * bf2f(r0[1024 + tid]) + aq.w * bf2f(r0[1536 + tid]);
      a1 += aq.x * bf2f(r0[256 + tid])  + aq.y * bf2f(r0[768 + tid])
          + aq.z * bf2f(r0[1280 + tid]) + aq.w * bf2f(r0[1792 + tid]);
    }
    ctx_s[tid] = a0; ctx_s[256 + tid] = a1;
    aslot1[b * 768 + tid] = a0; aslot1[b * 768 + 256 + tid] = a1;
    Abf[((size_t)t * 16 + b) * 768 + tid] = f2bf(a0);
    Abf[((size_t)t * 16 + b) * 768 + 256 + tid] = f2bf(a1);
  }
  float clp = 0.f, scp = 0.f;
  {
    int tg = tgt_ext[b * 50 + t];
    for (int s = tid; s < 400; s += 256){
      float a = at_s[s];
      float cv = coverage[b * 400 + s];
      clp += fminf(a, cv);
      coverage[b * 400 + s] = cv + a;
      if (src_ext[b * 400 + s] == tg) scp += a;
    }
  }
  __syncthreads();
  {
    float p = ctx_s[tid] * pgW[tid] + ctx_s[256 + tid] * pgW[256 + tid]
            + aslot1[b * 768 + 512 + tid] * pgW[512 + tid];
    float dsum = blk_sum(p, red_s);
    float cl = blk_sum(clp, red_s);
    float sc2 = blk_sum(scp, red_s);
    if (tid == 0){
      float pg = sigm(dsum + pg_emb[t * 16 + b] + pgb[0] + pgbias[0]);
      pg = fminf(fmaxf(pg, 0.1f), 0.9f);
      pg_t[b] = pg; cvl_t[b] = cl; sct_t[b] = sc2;
    }
  }
}

// ---------------- batched vocab ----------------
__global__ __launch_bounds__(256) void k_vgemm(const u16* __restrict__ Abf, const u16* __restrict__ vWt,
    const float* __restrict__ vb, const int* __restrict__ tgt_ext,
    float* __restrict__ mpart2, float* __restrict__ spart2, float* __restrict__ ltgt_all){
  int nslab = blockIdx.x, mslab = blockIdx.y;
  int tid = threadIdx.x;
  int w = tid >> 6, lane = tid & 63, q = lane & 15, r = lane >> 4;
  int m0 = mslab * 80;
  int n0w = nslab * 256 + w * 64;
  f32x4 acc[5][4];
#pragma unroll
  for (int mt = 0; mt < 5; ++mt)
#pragma unroll
    for (int nt = 0; nt < 4; ++nt){ acc[mt][nt][0]=0.f; acc[mt][nt][1]=0.f; acc[mt][nt][2]=0.f; acc[mt][nt][3]=0.f; }

  for (int kb = 0; kb < 24; ++kb){
    bf16x8 bfrag[4], afrag[5];
#pragma unroll
    for (int nt = 0; nt < 4; ++nt)
      bfrag[nt] = *(const bf16x8*)&vWt[(size_t)(n0w + nt * 16 + q) * 768 + kb * 32 + r * 8];
#pragma unroll
    for (int mt = 0; mt < 5; ++mt)
      afrag[mt] = *(const bf16x8*)&Abf[(size_t)(m0 + mt * 16 + q) * 768 + kb * 32 + r * 8];
#pragma unroll
    for (int mt = 0; mt < 5; ++mt)
#pragma unroll
      for (int nt = 0; nt < 4; ++nt)
        acc[mt][nt] = __builtin_amdgcn_mfma_f32_16x16x32_bf16(afrag[mt], bfrag[nt], acc[mt][nt], 0, 0, 0);
  }
  float vbc[4];
#pragma unroll
  for (int nt = 0; nt < 4; ++nt) vbc[nt] = vb[n0w + nt * 16 + q];

  __shared__ float pm[4][80], ps[4][80];
#pragma unroll
  for (int mt = 0; mt < 5; ++mt){
#pragma unroll
    for (int rg = 0; rg < 4; ++rg){
      int row = m0 + mt * 16 + 4 * r + rg;
      int tg = tgt_ext[(row & 15) * 50 + (row >> 4)];
      float v0 = acc[mt][0][rg] + vbc[0];
      float v1 = acc[mt][1][rg] + vbc[1];
      float v2 = acc[mt][2][rg] + vbc[2];
      float v3 = acc[mt][3][rg] + vbc[3];
      if (n0w + 0 * 16 + q == tg) ltgt_all[row] = v0;
      if (n0w + 1 * 16 + q == tg) ltgt_all[row] = v1;
      if (n0w + 2 * 16 + q == tg) ltgt_all[row] = v2;
      if (n0w + 3 * 16 + q == tg) ltgt_all[row] = v3;
      float mx = fmaxf(fmaxf(v0, v1), fmaxf(v2, v3));
#pragma unroll
      for (int mk = 1; mk < 16; mk <<= 1) mx = fmaxf(mx, __shfl_xor(mx, mk));
      float se = __expf(v0 - mx) + __expf(v1 - mx) + __expf(v2 - mx) + __expf(v3 - mx);
#pragma unroll
      for (int mk = 1; mk < 16; mk <<= 1) se += __shfl_xor(se, mk);
      if (q == 0){ pm[w][mt * 16 + 4 * r + rg] = mx; ps[w][mt * 16 + 4 * r + rg] = se; }
    }
  }
  __syncthreads();
  if (tid < 80){
    float m = pm[0][tid], s = ps[0][tid];
#pragma unroll
    for (int w2 = 1; w2 < 4; ++w2){
      float om = pm[w2][tid], os = ps[w2][tid];
      float M = fmaxf(m, om);
      s = s * __expf(m - M) + os * __expf(om - M);
      m = M;
    }
    mpart2[(size_t)(m0 + tid) * 125 + nslab] = m;
    spart2[(size_t)(m0 + tid) * 125 + nslab] = s;
  }
}

__global__ void k_comb2(const float* __restrict__ mpart2, const float* __restrict__ spart2,
                        const float* __restrict__ ltgt_all, const float* __restrict__ pg_all,
                        const float* __restrict__ cvl_all, const float* __restrict__ sct_all,
                        const int* __restrict__ tgt_ext, const float* __restrict__ lam,
                        float* __restrict__ loss_g, float* __restrict__ valid_g){
  int t = blockIdx.x; int tid = threadIdx.x;
  int b = tid >> 4, l16 = tid & 15;
  int row = t * 16 + b;
  float m = -1e30f, s = 0.f;
  for (int i = l16; i < 125; i += 16){
    float om = mpart2[(size_t)row * 125 + i], os = spart2[(size_t)row * 125 + i];
    float M = fmaxf(m, om);
    s = s * __expf(m - M) + os * __expf(om - M);
    m = M;
  }
#pragma unroll
  for (int mk = 1; mk < 16; mk <<= 1){
    float om = __shfl_xor(m, mk), os = __shfl_xor(s, mk);
    float M = fmaxf(m, om);
    s = s * __expf(m - M) + os * __expf(om - M);
    m = M;
  }
  if (l16 == 0){
    int tg = tgt_ext[b * 50 + t];
    float pv = (tg < 32000) ? (__expf(ltgt_all[row] - m) / s) : 0.f;
    float pg = pg_all[row];
    float pf = pg * pv + (1.f - pg) * sct_all[row];
    float sl = -__logf(pf + 1e-12f);
    float msk = (tg != 0) ? 1.f : 0.f;
    loss_g[row] = (sl + lam[0] * cvl_all[row]) * msk;
    valid_g[row] = msk;
  }
}

// ---------------- fallback per-step vocab (f32) ----------------
__global__ __launch_bounds__(256) void k_vocab(const float* __restrict__ adec, const float* __restrict__ vW,
    const float* __restrict__ vb, const int* __restrict__ tgt_ext, int t,
    float* __restrict__ mpart, float* __restrict__ spart, float* __restrict__ ltgt){
  int col0 = blockIdx.x * 128;
  int tid = threadIdx.x;
  int cl = tid & 127, half = tid >> 7;
  int col = col0 + cl;
  float acc[16];
#pragma unroll
  for (int i = 0; i < 16; ++i) acc[i] = 0.f;
  const float* Wc = vW + col;
  for (int k = half * 384; k < half * 384 + 384; k += 4){
    float w0 = Wc[(size_t)(k + 0) * 32000];
    float w1 = Wc[(size_t)(k + 1) * 32000];
    float w2 = Wc[(size_t)(k + 2) * 32000];
    float w3 = Wc[(size_t)(k + 3) * 32000];
#pragma unroll
    for (int b = 0; b < 16; ++b){
      const float* Ab = adec + b * 768 + k;
      acc[b] += Ab[0] * w0 + Ab[1] * w1 + Ab[2] * w2 + Ab[3] * w3;
    }
  }
  __shared__ float Ls[2][16][128];
#pragma unroll
  for (int b2 = 0; b2 < 16; ++b2) Ls[half][b2][cl] = acc[b2];
  __syncthreads();
  if (half == 0){
    float vbc = vb[col];
#pragma unroll
    for (int b2 = 0; b2 < 16; ++b2) Ls[0][b2][cl] = Ls[0][b2][cl] + Ls[1][b2][cl] + vbc;
  }
  __syncthreads();
  {
    int b2 = tid >> 4, l16 = tid & 15;
    float m = -1e30f, ssum = 0.f;
#pragma unroll
    for (int i = 0; i < 8; ++i){
      float x = Ls[0][b2][l16 + 16 * i];
      float M = fmaxf(m, x);
      ssum = ssum * __expf(m - M) + __expf(x - M);
      m = M;
    }
#pragma unroll
    for (int mk = 1; mk < 16; mk <<= 1){
      float om = __shfl_xor(m, mk), os = __shfl_xor(ssum, mk);
      float M = fmaxf(m, om);
      ssum = ssum * __expf(m - M) + os * __expf(om - M);
      m = M;
    }
    if (l16 == 0){ mpart[b2 * 250 + blockIdx.x] = m; spart[b2 * 250 + blockIdx.x] = ssum; }
  }
  if (tid < 16){
    int tg = tgt_ext[tid * 50 + t];
    unsigned offc = (unsigned)(tg - col0);
    if (offc < 128u) ltgt[tid] = Ls[0][tid][offc];
  }
}

__global__ void k_comb(const float* __restrict__ mpart, const float* __restrict__ spart,
                       const float* __restrict__ ltgt, const float* __restrict__ pg_g,
                       const float* __restrict__ cvl_g, const float* __restrict__ sct_g,
                       const int* __restrict__ tgt_ext, const float* __restrict__ lam, int t,
                       float* __restrict__ loss_g, float* __restrict__ valid_g){
  int tid = threadIdx.x;
  int b = tid >> 4, l16 = tid & 15;
  float m = -1e30f, s = 0.f;
  for (int i = l16; i < 250; i += 16){
    float om = mpart[b * 250 + i], os = spart[b * 250 + i];
    float M = fmaxf(m, om);
    s = s * __expf(m - M) + os * __expf(om - M);
    m = M;
  }
#pragma unroll
  for (int mk = 1; mk < 16; mk <<= 1){
    float om = __shfl_xor(m, mk), os = __shfl_xor(s, mk);
    float M = fmaxf(m, om);
    s = s * __expf(m - M) + os * __expf(om - M);
    m = M;
  }
  if (l16 == 0){
    int tg = tgt_ext[b * 50 + t];
    float pv = (tg < 32000) ? (__expf(ltgt[b] - m) / s) : 0.f;
    float pg = pg_g[b];
    float pf = pg * pv + (1.f - pg) * sct_g[b];
    float sl = -__logf(pf + 1e-12f);
    float msk = (tg != 0) ? 1.f : 0.f;
    loss_g[t * 16 + b] = (sl + lam[0] * cvl_g[b]) * msk;
    valid_g[t * 16 + b] = msk;
  }
}

__global__ void k_final(const float* __restrict__ loss_g, const float* __restrict__ valid_g, float* __restrict__ out){
  __shared__ float r1[256], r2[256];
  int tid = threadIdx.x;
  float a = 0.f, v = 0.f;
  for (int i = tid; i < 800; i += 256){ a += loss_g[i]; v += valid_g[i]; }
  r1[tid] = a; r2[tid] = v; __syncthreads();
  for (int off = 128; off; off >>= 1){
    if (tid < off){ r1[tid] += r1[tid + off]; r2[tid] += r2[tid + off]; }
    __syncthreads();
  }
  if (tid == 0) out[0] = r1[0] / fmaxf(r2[0], 1.f);
}

extern "C" void kernel_launch(void* const* d_in, const int* in_sizes, int n_in,
                              void* d_out, int out_size, void* d_ws, size_t ws_size,
                              hipStream_t stream){
  const int*   src     = (const int*)  d_in[0];
  const int*   src_ext = (const int*)  d_in[1];
  const int*   dec_in  = (const int*)  d_in[2];
  const int*   tgt_ext = (const int*)  d_in[3];
  const float* enc_emb = (const float*)d_in[5];
  const float* eWihF   = (const float*)d_in[6];
  const float* eWhhF   = (const float*)d_in[7];
  const float* ebF     = (const float*)d_in[8];
  const float* eWihB   = (const float*)d_in[9];
  const float* eWhhB   = (const float*)d_in[10];
  const float* ebB     = (const float*)d_in[11];
  const float* rhW     = (const float*)d_in[12];
  const float* rhb     = (const float*)d_in[13];
  const float* rcW     = (const float*)d_in[14];
  const float* rcb     = (const float*)d_in[15];
  const float* dec_emb = (const float*)d_in[16];
  const float* dWih    = (const float*)d_in[17];
  const float* dWhh    = (const float*)d_in[18];
  const float* db_     = (const float*)d_in[19];
  const float* aWh     = (const float*)d_in[20];
  const float* aWs     = (const float*)d_in[21];
  const float* aWsb    = (const float*)d_in[22];
  const float* aWc     = (const float*)d_in[23];
  const float* av      = (const float*)d_in[24];
  const float* pgW     = (const float*)d_in[25];
  const float* pgb     = (const float*)d_in[26];
  const float* vW      = (const float*)d_in[27];
  const float* vb      = (const float*)d_in[28];
  const float* lam     = (const float*)d_in[29];
  const float* pgbias  = (const float*)d_in[30];
  (void)in_sizes; (void)n_in; (void)out_size;

  char* w = (char*)d_ws;
  size_t off = 0;
  auto alloc = [&](size_t bytes) -> char* {
    char* p = w + off; off += (bytes + 255) & ~(size_t)255; return p;
  };
  u16*     xw      = (u16*)    alloc(2ull * 400 * 1024 * 16 * 2);
  u16*     whhp    = (u16*)    alloc(2ull * 1024 * 256 * 2);
  ushort4* decwp   = (ushort4*)alloc(768ull * 256 * 8);
  u16*     enc_out = (u16*)    alloc(16ull * 400 * 512 * 2);
  u16*     feat    = (u16*)    alloc(16ull * 400 * 256 * 2);
  float*   hfin    = (float*)  alloc(2 * 16 * 256 * 4);
  float*   cfin    = (float*)  alloc(2 * 16 * 256 * 4);
  float*   cbuf    = (float*)  alloc(2 * 16 * 256 * 4);
  float4*  xwd     = (float4*) alloc(50ull * 16 * 256 * 16);
  float*   pg_emb  = (float*)  alloc(800 * 4);
  u32*     hxch    = (u32*)    alloc(2ull * 2 * 16 * 256 * 4);   // 64 KB h exchange
  u32*     bar     = (u32*)    alloc(2 * 64 * 4);                // spin counters
  float*   coverage= (float*)  alloc(16 * 400 * 4);
  float*   astore  = (float*)  alloc(51ull * 16 * 768 * 4);
  u16*     Abf     = (u16*)    alloc(800ull * 768 * 2);          // bf16 A, written in-loop
  float*   mpartF  = (float*)  alloc(16 * 250 * 4);
  float*   spartF  = (float*)  alloc(16 * 250 * 4);
  float*   ltgt_all= (float*)  alloc(800 * 4);
  float*   pg_all  = (float*)  alloc(800 * 4);
  float*   cvl_all = (float*)  alloc(800 * 4);
  float*   sct_all = (float*)  alloc(800 * 4);
  float*   loss_g  = (float*)  alloc(800 * 4);
  float*   valid_g = (float*)  alloc(800 * 4);
  // batched-vocab extras at the end so the fallback path never needs them
  float*   mpart2  = (float*)  alloc(800ull * 125 * 4);
  float*   spart2  = (float*)  alloc(800ull * 125 * 4);
  u16*     vWt     = (u16*)    alloc(32000ull * 768 * 2);
  bool use_batched = (off <= ws_size);

  // zero coverage + astore slot0 (contiguous), and the encoder barrier counters
  hipMemsetAsync(coverage, 0, 16 * 400 * 4 + 16 * 768 * 4, stream);
  hipMemsetAsync(bar, 0, 2 * 64 * 4, stream);

  hipLaunchKernelGGL(k_pack_whh2, dim3(2048),  dim3(256), 0, stream, eWhhF, eWhhB, whhp);
  hipLaunchKernelGGL(k_pack_decw, dim3(768),   dim3(256), 0, stream, dWih, dWhh, decwp);
  if (use_batched)
    hipLaunchKernelGGL(k_pack_vwt, dim3(500, 12), dim3(256), 0, stream, vW, vWt);
  hipLaunchKernelGGL(k_enc_pre2,  dim3(800),   dim3(256), 0, stream, src, enc_emb, eWihF, ebF, eWihB, ebB, xw);
  hipLaunchKernelGGL(k_dec_pre,   dim3(800),   dim3(256), 0, stream, dec_in, dec_emb, dWih, db_, pgW, xwd, pg_emb);
  hipLaunchKernelGGL(k_enc_lstm3, dim3(16),    dim3(256), 0, stream, xw, whhp, enc_out, hfin, cfin, hxch, bar);
  hipLaunchKernelGGL(k_reduce,    dim3(16),    dim3(256), 0, stream, hfin, cfin, rhW, rhb, rcW, rcb, astore, cbuf);
  hipLaunchKernelGGL(k_encfeat,   dim3(400),   dim3(256), 0, stream, enc_out, aWh, feat);

  for (int t = 0; t < 50; ++t){
    float* aslot0 = astore + (size_t)t * 16 * 768;
    float* aslot1 = astore + (size_t)(t + 1) * 16 * 768;
    float* cin  = cbuf + (t & 1) * 16 * 256;
    float* cout = cbuf + ((t + 1) & 1) * 16 * 256;
    hipLaunchKernelGGL(k_cell,  dim3(64),  dim3(256), 0, stream, aslot0, cin, decwp, xwd, t, aslot1, cout, Abf);
    hipLaunchKernelGGL(k_attn,  dim3(16),  dim3(256), 0, stream, aslot1, feat, enc_out, src, src_ext, tgt_ext,
                       aWs, aWsb, aWc, av, pgW, pg_emb, pgb, pgbias, coverage, Abf,
                       pg_all + t * 16, cvl_all + t * 16, sct_all + t * 16, t);
    if (!use_batched){
      hipLaunchKernelGGL(k_vocab, dim3(250), dim3(256), 0, stream, aslot1, vW, vb, tgt_ext, t, mpartF, spartF, ltgt_all + t * 16);
      hipLaunchKernelGGL(k_comb,  dim3(1),   dim3(256), 0, stream, mpartF, spartF, ltgt_all + t * 16,
                         pg_all + t * 16, cvl_all + t * 16, sct_all + t * 16, tgt_ext, lam, t, loss_g, valid_g);
    }
  }
  if (use_batched){
    hipLaunchKernelGGL(k_vgemm,  dim3(125, 10), dim3(256), 0, stream, Abf, vWt, vb, tgt_ext, mpart2, spart2, ltgt_all);
    hipLaunchKernelGGL(k_comb2,  dim3(50), dim3(256), 0, stream, mpart2, spart2, ltgt_all,
                       pg_all, cvl_all, sct_all, tgt_ext, lam, loss_g, valid_g);
  }
  hipLaunchKernelGGL(k_final, dim3(1), dim3(256), 0, stream, loss_g, valid_g, (float*)d_out);
}

// Round 5
// 5156.993 us; speedup vs baseline: 2.9570x; 1.4683x over previous
//
#include <hip/hip_runtime.h>
#include <math.h>

typedef unsigned short u16;
typedef unsigned int   u32;
typedef unsigned long long u64;
typedef __attribute__((ext_vector_type(8))) short bf16x8;
typedef __attribute__((ext_vector_type(4))) float f32x4;

#define DEVI static __device__ __forceinline__

DEVI float bf2f(u16 u){ u32 x = ((u32)u) << 16; float f; __builtin_memcpy(&f, &x, 4); return f; }
DEVI u16 f2bf(float f){ u32 x; __builtin_memcpy(&x, &f, 4); u32 r = (x + 0x7fffu + ((x >> 16) & 1u)) >> 16; return (u16)r; }
DEVI float sigm(float x){ return 1.f / (1.f + __expf(-x)); }
DEVI float tanh_f(float x){ float e = __expf(2.f * x); return 1.f - 2.f / (e + 1.f); }

// ---------------- pack kernels ----------------
__global__ void k_pack_whh2(const float* __restrict__ Wf, const float* __restrict__ Wb, u16* __restrict__ out){
  int blk = blockIdx.x;             // 2*1024
  int d = blk >> 10, n = blk & 1023;
  const float* W = d ? Wb : Wf;
  int k = threadIdx.x;
  out[((size_t)d * 1024 + n) * 256 + k] = f2bf(W[(size_t)k * 1024 + n]);
}

__global__ void k_pack_decw(const float* __restrict__ Wih, const float* __restrict__ Whh, ushort4* __restrict__ out){
  int idx = blockIdx.x * 256 + threadIdx.x;      // 768*256
  int k = idx >> 8, j = idx & 255;
  const float* row = (k < 512) ? (Wih + (size_t)(128 + k) * 1024) : (Whh + (size_t)(k - 512) * 1024);
  ushort4 r;
  r.x = f2bf(row[j]);       r.y = f2bf(row[256 + j]);
  r.z = f2bf(row[512 + j]); r.w = f2bf(row[768 + j]);
  out[idx] = r;
}

// vW [768][32000] f32 -> vWt [32000][768] bf16
__global__ __launch_bounds__(256) void k_pack_vwt(const float* __restrict__ vW, u16* __restrict__ vWt){
  __shared__ float ts[64][65];
  int nt = blockIdx.x, kt = blockIdx.y;   // 500 x 12
  int tid = threadIdx.x;
#pragma unroll
  for (int i = 0; i < 16; ++i){
    int idx = tid + i * 256;
    int kl = idx >> 6, nl = idx & 63;
    ts[kl][nl] = vW[(size_t)(kt * 64 + kl) * 32000 + nt * 64 + nl];
  }
  __syncthreads();
#pragma unroll
  for (int i = 0; i < 16; ++i){
    int idx = tid + i * 256;
    int nl = idx >> 6, kl = idx & 63;
    vWt[(size_t)(nt * 64 + nl) * 768 + kt * 64 + kl] = f2bf(ts[kl][nl]);
  }
}

// ---------------- encoder ----------------
// xw[d][s][n][b] bf16 of emb@Wih + bias   (n = gate*256 + hc)
__global__ __launch_bounds__(256) void k_enc_pre2(const int* __restrict__ src, const float* __restrict__ emb,
                          const float* __restrict__ Wf, const float* __restrict__ bf_,
                          const float* __restrict__ Wb, const float* __restrict__ bb_,
                          u16* __restrict__ xw){
  int d = blockIdx.x / 400, s = blockIdx.x % 400;
  const float* Wih = d ? Wb : Wf; const float* bias = d ? bb_ : bf_;
  __shared__ float es[16][128];
  int tid = threadIdx.x;
  for (int idx = tid; idx < 16 * 128; idx += 256){
    int b = idx >> 7, e = idx & 127;
    es[b][e] = emb[(size_t)src[b * 400 + s] * 128 + e];
  }
  __syncthreads();
  int j = tid;
  float a[4][16];
#pragma unroll
  for (int g = 0; g < 4; ++g){
    float bv = bias[g * 256 + j];
#pragma unroll
    for (int b = 0; b < 16; ++b) a[g][b] = bv;
  }
  for (int e4 = 0; e4 < 32; ++e4){
    float w0[4], w1[4], w2[4], w3[4];
#pragma unroll
    for (int u = 0; u < 4; ++u){
      int e = e4 * 4 + u;
      w0[u] = Wih[(size_t)e * 1024 + j];
      w1[u] = Wih[(size_t)e * 1024 + 256 + j];
      w2[u] = Wih[(size_t)e * 1024 + 512 + j];
      w3[u] = Wih[(size_t)e * 1024 + 768 + j];
    }
#pragma unroll
    for (int b = 0; b < 16; ++b){
      float4 x = *(const float4*)&es[b][e4 * 4];
      a[0][b] += x.x * w0[0] + x.y * w0[1] + x.z * w0[2] + x.w * w0[3];
      a[1][b] += x.x * w1[0] + x.y * w1[1] + x.z * w1[2] + x.w * w1[3];
      a[2][b] += x.x * w2[0] + x.y * w2[1] + x.z * w2[2] + x.w * w2[3];
      a[3][b] += x.x * w3[0] + x.y * w3[1] + x.z * w3[2] + x.w * w3[3];
    }
  }
#pragma unroll
  for (int g = 0; g < 4; ++g){
    u16 tmp[16];
#pragma unroll
    for (int b = 0; b < 16; ++b) tmp[b] = f2bf(a[g][b]);
    uint4* dst = (uint4*)&xw[(((size_t)(d * 400 + s)) * 1024 + g * 256 + j) * 16];
    dst[0] = *(uint4*)&tmp[0];
    dst[1] = *(uint4*)&tmp[8];
  }
}

// Encoder LSTM: 4 blocks (2 dir x 2 hc-halves), 512 thr (8 waves).
// Each block: 128 hc x 4 gates, Whh slice in registers (wreg[4][8] = 128 VGPR).
// Pairwise h exchange (8KB packed hi/lo) via agent atomics + release/acquire flag.
__global__ __launch_bounds__(512, 2) void k_enc_lstm4(
    const u16* __restrict__ xw, const u16* __restrict__ wpk,
    u16* __restrict__ enc_out, float* __restrict__ hfin, float* __restrict__ cfin,
    u32* __restrict__ hpub, u32* __restrict__ flags)
{
  const int blk = blockIdx.x;
  const int d = blk >> 1, bp = blk & 1;
  const int tid = threadIdx.x;
  const int w = tid >> 6, lane = tid & 63;
  const int q = lane & 15, r = lane >> 4;
  const int g = w >> 1, sub = w & 1;

  __shared__ u16 hhi[16][264];
  __shared__ u16 hlo[16][264];
  __shared__ float gex[4][16][132];

  for (int idx = tid; idx < 16 * 264; idx += 512){
    hhi[idx / 264][idx % 264] = 0;
    hlo[idx / 264][idx % 264] = 0;
  }

  const u16* wb = wpk + (size_t)d * 1024 * 256;
  int nn[4];
  bf16x8 wreg[4][8];
#pragma unroll
  for (int nt = 0; nt < 4; ++nt){
    nn[nt] = g * 256 + bp * 128 + sub * 64 + nt * 16 + q;
#pragma unroll
    for (int kb = 0; kb < 8; ++kb)
      wreg[nt][kb] = *(const bf16x8*)&wb[(size_t)nn[nt] * 256 + kb * 32 + r * 8];
  }

  const int cb = tid >> 5;            // batch 0..15
  const int i4 = (tid & 31) * 4;      // local hc base
  float c[4] = {0.f, 0.f, 0.f, 0.f}, hl[4] = {0.f, 0.f, 0.f, 0.f};

  u32* myflag = flags + (d * 2 + bp) * 32;
  u32* rmflag = flags + (d * 2 + (bp ^ 1)) * 32;

  int s0 = d ? 399 : 0;
  ushort4 xv[4];
#pragma unroll
  for (int nt = 0; nt < 4; ++nt)
    xv[nt] = *(const ushort4*)&xw[(((size_t)(d * 400 + s0)) * 1024 + nn[nt]) * 16 + 4 * r];
  __syncthreads();

  for (int it = 0; it < 400; ++it){
    int s = d ? (399 - it) : it;
    f32x4 acc[4];
#pragma unroll
    for (int nt = 0; nt < 4; ++nt){
      acc[nt][0] = bf2f(xv[nt].x); acc[nt][1] = bf2f(xv[nt].y);
      acc[nt][2] = bf2f(xv[nt].z); acc[nt][3] = bf2f(xv[nt].w);
    }
#pragma unroll
    for (int kb = 0; kb < 8; ++kb){
      bf16x8 ah = *(const bf16x8*)&hhi[q][kb * 32 + r * 8];
      bf16x8 al = *(const bf16x8*)&hlo[q][kb * 32 + r * 8];
#pragma unroll
      for (int nt = 0; nt < 4; ++nt){
        acc[nt] = __builtin_amdgcn_mfma_f32_16x16x32_bf16(ah, wreg[nt][kb], acc[nt], 0, 0, 0);
        acc[nt] = __builtin_amdgcn_mfma_f32_16x16x32_bf16(al, wreg[nt][kb], acc[nt], 0, 0, 0);
      }
    }
    // gate exchange: (b = 4r+rg, hc-local = sub*64+nt*16+q)
#pragma unroll
    for (int nt = 0; nt < 4; ++nt)
#pragma unroll
      for (int rg = 0; rg < 4; ++rg)
        gex[g][4 * r + rg][sub * 64 + nt * 16 + q] = acc[nt][rg];
    __syncthreads();

    // combine 4 cells per thread
    u32 pk[4];
#pragma unroll
    for (int j = 0; j < 4; ++j){
      int hcl = i4 + j;
      float gi = gex[0][cb][hcl], gf = gex[1][cb][hcl];
      float gg = gex[2][cb][hcl], go = gex[3][cb][hcl];
      float cv = sigm(gf) * c[j] + sigm(gi) * tanh_f(gg);
      float hv = sigm(go) * tanh_f(cv);
      c[j] = cv; hl[j] = hv;
      u16 hi = f2bf(hv);
      u16 lo = f2bf(hv - bf2f(hi));
      pk[j] = ((u32)hi << 16) | lo;
    }
    // local h (hi/lo) + enc_out
    {
      u64 hi64 = (u64)(pk[0] >> 16) | ((u64)(pk[1] >> 16) << 16)
               | ((u64)(pk[2] >> 16) << 32) | ((u64)(pk[3] >> 16) << 48);
      u64 lo64 = (u64)(pk[0] & 0xffffu) | ((u64)(pk[1] & 0xffffu) << 16)
               | ((u64)(pk[2] & 0xffffu) << 32) | ((u64)(pk[3] & 0xffffu) << 48);
      *(u64*)&hhi[cb][bp * 128 + i4] = hi64;
      *(u64*)&hlo[cb][bp * 128 + i4] = lo64;
      *(u64*)&enc_out[((size_t)cb * 400 + s) * 512 + d * 256 + bp * 128 + i4] = hi64;
    }
    if (it < 399){
      int par = (it + 1) & 1;
      u32* hp_w = hpub + (((size_t)par * 2 + d) * 2 + bp) * 2048;
#pragma unroll
      for (int j = 0; j < 4; ++j)
        __hip_atomic_store(&hp_w[cb * 128 + i4 + j], pk[j], __ATOMIC_RELAXED, __HIP_MEMORY_SCOPE_AGENT);
      // prefetch next x under the sync
      int sn = d ? (399 - (it + 1)) : (it + 1);
#pragma unroll
      for (int nt = 0; nt < 4; ++nt)
        xv[nt] = *(const ushort4*)&xw[(((size_t)(d * 400 + sn)) * 1024 + nn[nt]) * 16 + 4 * r];
      __syncthreads();   // drains all threads' hpub stores (vmcnt) + local LDS writes
      if (tid == 0){
        __hip_atomic_store(myflag, (u32)(it + 1), __ATOMIC_RELEASE, __HIP_MEMORY_SCOPE_AGENT);
        while (__hip_atomic_load(rmflag, __ATOMIC_ACQUIRE, __HIP_MEMORY_SCOPE_AGENT) < (u32)(it + 1))
          __builtin_amdgcn_s_sleep(1);
      }
      __syncthreads();
      // read remote 8KB half
      const u32* hp_r = hpub + (((size_t)par * 2 + d) * 2 + (bp ^ 1)) * 2048;
      u32 rp[4];
#pragma unroll
      for (int j = 0; j < 4; ++j)
        rp[j] = __hip_atomic_load(&hp_r[cb * 128 + i4 + j], __ATOMIC_RELAXED, __HIP_MEMORY_SCOPE_AGENT);
      u64 hi64 = (u64)(rp[0] >> 16) | ((u64)(rp[1] >> 16) << 16)
               | ((u64)(rp[2] >> 16) << 32) | ((u64)(rp[3] >> 16) << 48);
      u64 lo64 = (u64)(rp[0] & 0xffffu) | ((u64)(rp[1] & 0xffffu) << 16)
               | ((u64)(rp[2] & 0xffffu) << 32) | ((u64)(rp[3] & 0xffffu) << 48);
      *(u64*)&hhi[cb][(bp ^ 1) * 128 + i4] = hi64;
      *(u64*)&hlo[cb][(bp ^ 1) * 128 + i4] = lo64;
      __syncthreads();
    }
  }
#pragma unroll
  for (int j = 0; j < 4; ++j){
    hfin[(d * 16 + cb) * 256 + bp * 128 + i4 + j] = hl[j];
    cfin[(d * 16 + cb) * 256 + bp * 128 + i4 + j] = c[j];
  }
}

// reduce -> h0buf, c0buf
__global__ void k_reduce(const float* __restrict__ hfin, const float* __restrict__ cfin,
                         const float* __restrict__ rhW, const float* __restrict__ rhb,
                         const float* __restrict__ rcW, const float* __restrict__ rcb,
                         float* __restrict__ h0buf, float* __restrict__ c0buf){
  int b = blockIdx.x, j = threadIdx.x;
  float ah = rhb[j], ac = rcb[j];
  for (int k = 0; k < 256; ++k){
    float hv = hfin[b * 256 + k], cv = cfin[b * 256 + k];
    ah += hv * rhW[k * 256 + j];
    ac += cv * rcW[k * 256 + j];
  }
  for (int k = 0; k < 256; ++k){
    float hv = hfin[(16 + b) * 256 + k], cv = cfin[(16 + b) * 256 + k];
    ah += hv * rhW[(256 + k) * 256 + j];
    ac += cv * rcW[(256 + k) * 256 + j];
  }
  h0buf[b * 256 + j] = tanh_f(ah);
  c0buf[b * 256 + j] = tanh_f(ac);
}

__global__ void k_encfeat(const u16* __restrict__ enc_out, const float* __restrict__ Wh, u16* __restrict__ feat){
  int blk = blockIdx.x; int b = blk / 25; int sc = blk % 25;
  int j = threadIdx.x;
  float acc[16];
#pragma unroll
  for (int i = 0; i < 16; ++i) acc[i] = 0.f;
  const u32* ebase = (const u32*)(enc_out + ((size_t)b * 400 + sc * 16) * 512);
  for (int k2 = 0; k2 < 256; ++k2){
    float wa = Wh[(2 * k2) * 256 + j], wb_ = Wh[(2 * k2 + 1) * 256 + j];
#pragma unroll
    for (int ss = 0; ss < 16; ++ss){
      u32 p = ebase[ss * 256 + k2];
      acc[ss] += bf2f((u16)(p & 0xffff)) * wa + bf2f((u16)(p >> 16)) * wb_;
    }
  }
#pragma unroll
  for (int ss = 0; ss < 16; ++ss)
    feat[((size_t)b * 400 + sc * 16 + ss) * 256 + j] = f2bf(acc[ss]);
}

// ---------------- decoder precompute ----------------
__global__ void k_dec_pre(const int* __restrict__ din, const float* __restrict__ emb,
                          const float* __restrict__ Wih, const float* __restrict__ db,
                          const float* __restrict__ pgW,
                          float4* __restrict__ xwd, float* __restrict__ pg_emb){
  int blk = blockIdx.x; int t = blk / 16, b = blk % 16;
  int j = threadIdx.x;
  int id = din[b * 50 + t];
  const float* er = emb + (size_t)id * 128;
  float a0 = db[j], a1 = db[256 + j], a2 = db[512 + j], a3 = db[768 + j];
  for (int e = 0; e < 128; ++e){
    float x = er[e];
    const float* wr = Wih + (size_t)e * 1024;
    a0 += x * wr[j]; a1 += x * wr[256 + j]; a2 += x * wr[512 + j]; a3 += x * wr[768 + j];
  }
  xwd[(size_t)blk * 256 + j] = make_float4(a0, a1, a2, a3);
  __shared__ float red[256];
  float pe = 0.f;
  if (j < 128) pe = er[j] * pgW[768 + j];
  red[j] = pe; __syncthreads();
  for (int off = 128; off; off >>= 1){ if (j < off) red[j] += red[j + off]; __syncthreads(); }
  if (j == 0) pg_emb[blk] = red[0];
}

// ---------------- persistent decoder loop: 16 blocks (1 per batch), 1024 thr ----------------
__global__ __launch_bounds__(1024, 4) void k_dec_loop(
    const ushort4* __restrict__ decwp, const float4* __restrict__ xwd,
    const float* __restrict__ h0buf, const float* __restrict__ c0buf,
    const u16* __restrict__ feat, const u16* __restrict__ enc_out,
    const int* __restrict__ src, const int* __restrict__ src_ext, const int* __restrict__ tgt_ext,
    const float* __restrict__ Ws, const float* __restrict__ Wsb,
    const float* __restrict__ Wc, const float* __restrict__ av_,
    const float* __restrict__ pgW, const float* __restrict__ pg_emb,
    const float* __restrict__ pgb, const float* __restrict__ pgbias,
    u16* __restrict__ Abf, float* __restrict__ pg_all,
    float* __restrict__ cvl_all, float* __restrict__ sct_all)
{
  const int b = blockIdx.x;
  const int tid = threadIdx.x;
  const int w = tid >> 6, L = tid & 63;

  __shared__ float a_lds[768];      // [ctx(512); h(256)]
  __shared__ float c_lds[256];
  __shared__ float cov[400];
  __shared__ float part[4][256][4]; // 16KB, aliased as partf[4096]
  __shared__ float hws[256];
  __shared__ float sc_s[400];
  __shared__ float at_s[400];
  __shared__ float red1[16], red2[16], red3[16];
  float* partf = &part[0][0][0];

  for (int i = tid; i < 512; i += 1024) a_lds[i] = 0.f;
  if (tid < 256){ a_lds[512 + tid] = h0buf[b * 256 + tid]; c_lds[tid] = c0buf[b * 256 + tid]; }
  for (int i = tid; i < 400; i += 1024) cov[i] = 0.f;
  float4 wc4 = *(const float4*)&Wc[4 * L];
  float4 vv4 = *(const float4*)&av_[4 * L];
  __syncthreads();

  for (int t = 0; t < 50; ++t){
    // P1: gate GEMM  g[1024] = a(768) @ decwp
    {
      int j = tid & 255, ks = tid >> 8;
      float g0 = 0.f, g1 = 0.f, g2 = 0.f, g3 = 0.f;
      const ushort4* wb = decwp + j;
      for (int k = ks * 192; k < ks * 192 + 192; ++k){
        ushort4 wv = wb[(size_t)k * 256];
        float a = a_lds[k];
        g0 += a * bf2f(wv.x); g1 += a * bf2f(wv.y);
        g2 += a * bf2f(wv.z); g3 += a * bf2f(wv.w);
      }
      part[ks][j][0] = g0; part[ks][j][1] = g1; part[ks][j][2] = g2; part[ks][j][3] = g3;
    }
    __syncthreads();
    if (tid < 256){
      float4 xv = xwd[((size_t)t * 16 + b) * 256 + tid];
      float s0 = xv.x + part[0][tid][0] + part[1][tid][0] + part[2][tid][0] + part[3][tid][0];
      float s1 = xv.y + part[0][tid][1] + part[1][tid][1] + part[2][tid][1] + part[3][tid][1];
      float s2 = xv.z + part[0][tid][2] + part[1][tid][2] + part[2][tid][2] + part[3][tid][2];
      float s3 = xv.w + part[0][tid][3] + part[1][tid][3] + part[2][tid][3] + part[3][tid][3];
      float cv = sigm(s1) * c_lds[tid] + sigm(s0) * tanh_f(s2);
      float hv = sigm(s3) * tanh_f(cv);
      c_lds[tid] = cv;
      a_lds[512 + tid] = hv;
      Abf[((size_t)t * 16 + b) * 768 + 512 + tid] = f2bf(hv);
    }
    __syncthreads();
    // P2: hws = Wsb + h @ Ws
    {
      int j2 = tid & 255, kq = tid >> 8;
      float acc = 0.f;
      for (int k = kq * 64; k < kq * 64 + 64; ++k) acc += a_lds[512 + k] * Ws[k * 256 + j2];
      partf[kq * 256 + j2] = acc;
    }
    __syncthreads();
    if (tid < 256) hws[tid] = Wsb[tid] + partf[tid] + partf[256 + tid] + partf[512 + tid] + partf[768 + tid];
    __syncthreads();
    // P3: scores over s (wave-per-s, 25 per wave)
    {
      float4 hw4 = *(const float4*)&hws[4 * L];
      for (int s = w; s < 400; s += 16){
        float cvv = cov[s];
        const u16* fp = feat + ((size_t)b * 400 + s) * 256 + 4 * L;
        u32 p0 = *(const u32*)fp; u32 p1 = *(const u32*)(fp + 2);
        float f0 = bf2f((u16)(p0 & 0xffff)) + hw4.x + cvv * wc4.x;
        float f1 = bf2f((u16)(p0 >> 16))    + hw4.y + cvv * wc4.y;
        float f2 = bf2f((u16)(p1 & 0xffff)) + hw4.z + cvv * wc4.z;
        float f3 = bf2f((u16)(p1 >> 16))    + hw4.w + cvv * wc4.w;
        float scv = tanh_f(f0) * vv4.x + tanh_f(f1) * vv4.y + tanh_f(f2) * vv4.z + tanh_f(f3) * vv4.w;
#pragma unroll
        for (int m = 32; m; m >>= 1) scv += __shfl_xor(scv, m);
        if (L == 0) sc_s[s] = (src[b * 400 + s] == 0) ? -1e9f : scv;
      }
    }
    __syncthreads();
    // P4: softmax over 400
    {
      float mv = (tid < 400) ? sc_s[tid] : -1e30f;
#pragma unroll
      for (int m = 32; m; m >>= 1) mv = fmaxf(mv, __shfl_xor(mv, m));
      if (L == 0) red1[w] = mv;
      __syncthreads();
      float mx = red1[0];
#pragma unroll
      for (int i = 1; i < 16; ++i) mx = fmaxf(mx, red1[i]);
      float ev = 0.f;
      if (tid < 400){ ev = __expf(sc_s[tid] - mx); at_s[tid] = ev; }
#pragma unroll
      for (int m = 32; m; m >>= 1) ev += __shfl_xor(ev, m);
      if (L == 0) red2[w] = ev;
      __syncthreads();
      float sum = 0.f;
#pragma unroll
      for (int i = 0; i < 16; ++i) sum += red2[i];
      float inv = 1.f / sum;
      if (tid < 400) at_s[tid] *= inv;
    }
    __syncthreads();
    // P5: context = attn @ enc_out  (col-pair per thread, 4-way s-split)
    {
      int c2 = (tid & 255) * 2, sh = tid >> 8;
      float a0 = 0.f, a1 = 0.f;
      const u16* eb = enc_out + (size_t)b * 400 * 512 + c2;
      for (int s = sh * 100; s < sh * 100 + 100; ++s){
        u32 p = *(const u32*)&eb[(size_t)s * 512];
        float av = at_s[s];
        a0 += av * bf2f((u16)(p & 0xffff));
        a1 += av * bf2f((u16)(p >> 16));
      }
      partf[sh * 1024 + c2] = a0;
      partf[sh * 1024 + c2 + 1] = a1;
    }
    __syncthreads();
    if (tid < 512){
      float cval = partf[tid] + partf[1024 + tid] + partf[2048 + tid] + partf[3072 + tid];
      a_lds[tid] = cval;
      Abf[((size_t)t * 16 + b) * 768 + tid] = f2bf(cval);
    }
    __syncthreads();
    // P6: coverage loss/update/scatter + pgen
    {
      float clp = 0.f, scp = 0.f, pgp = 0.f;
      int tg = tgt_ext[b * 50 + t];
      if (tid < 400){
        float a = at_s[tid];
        float cvv = cov[tid];
        clp = fminf(a, cvv);
        cov[tid] = cvv + a;
        if (src_ext[b * 400 + tid] == tg) scp = a;
      }
      if (tid < 768) pgp = a_lds[tid] * pgW[tid];
#pragma unroll
      for (int m = 32; m; m >>= 1){
        clp += __shfl_xor(clp, m);
        scp += __shfl_xor(scp, m);
        pgp += __shfl_xor(pgp, m);
      }
      if (L == 0){ red1[w] = clp; red2[w] = scp; red3[w] = pgp; }
      __syncthreads();
      if (tid == 0){
        float cl = 0.f, sc2 = 0.f, pgs = 0.f;
#pragma unroll
        for (int i = 0; i < 16; ++i){ cl += red1[i]; sc2 += red2[i]; pgs += red3[i]; }
        float pg = sigm(pgs + pg_emb[t * 16 + b] + pgb[0] + pgbias[0]);
        pg = fminf(fmaxf(pg, 0.1f), 0.9f);
        pg_all[t * 16 + b] = pg; cvl_all[t * 16 + b] = cl; sct_all[t * 16 + b] = sc2;
      }
    }
    __syncthreads();
  }
}

// ---------------- batched vocab ----------------
__global__ __launch_bounds__(256) void k_vgemm(const u16* __restrict__ Abf, const u16* __restrict__ vWt,
    const float* __restrict__ vb, const int* __restrict__ tgt_ext,
    float* __restrict__ mpart2, float* __restrict__ spart2, float* __restrict__ ltgt_all){
  int nslab = blockIdx.x, mslab = blockIdx.y;
  int tid = threadIdx.x;
  int w = tid >> 6, lane = tid & 63, q = lane & 15, r = lane >> 4;
  int m0 = mslab * 80;
  int n0w = nslab * 256 + w * 64;
  f32x4 acc[5][4];
#pragma unroll
  for (int mt = 0; mt < 5; ++mt)
#pragma unroll
    for (int nt = 0; nt < 4; ++nt){ acc[mt][nt][0]=0.f; acc[mt][nt][1]=0.f; acc[mt][nt][2]=0.f; acc[mt][nt][3]=0.f; }

  for (int kb = 0; kb < 24; ++kb){
    bf16x8 bfrag[4], afrag[5];
#pragma unroll
    for (int nt = 0; nt < 4; ++nt)
      bfrag[nt] = *(const bf16x8*)&vWt[(size_t)(n0w + nt * 16 + q) * 768 + kb * 32 + r * 8];
#pragma unroll
    for (int mt = 0; mt < 5; ++mt)
      afrag[mt] = *(const bf16x8*)&Abf[(size_t)(m0 + mt * 16 + q) * 768 + kb * 32 + r * 8];
#pragma unroll
    for (int mt = 0; mt < 5; ++mt)
#pragma unroll
      for (int nt = 0; nt < 4; ++nt)
        acc[mt][nt] = __builtin_amdgcn_mfma_f32_16x16x32_bf16(afrag[mt], bfrag[nt], acc[mt][nt], 0, 0, 0);
  }
  float vbc[4];
#pragma unroll
  for (int nt = 0; nt < 4; ++nt) vbc[nt] = vb[n0w + nt * 16 + q];

  __shared__ float pm[4][80], ps[4][80];
#pragma unroll
  for (int mt = 0; mt < 5; ++mt){
#pragma unroll
    for (int rg = 0; rg < 4; ++rg){
      int row = m0 + mt * 16 + 4 * r + rg;
      int tg = tgt_ext[(row & 15) * 50 + (row >> 4)];
      float v0 = acc[mt][0][rg] + vbc[0];
      float v1 = acc[mt][1][rg] + vbc[1];
      float v2 = acc[mt][2][rg] + vbc[2];
      float v3 = acc[mt][3][rg] + vbc[3];
      if (n0w + 0 * 16 + q == tg) ltgt_all[row] = v0;
      if (n0w + 1 * 16 + q == tg) ltgt_all[row] = v1;
      if (n0w + 2 * 16 + q == tg) ltgt_all[row] = v2;
      if (n0w + 3 * 16 + q == tg) ltgt_all[row] = v3;
      float mx = fmaxf(fmaxf(v0, v1), fmaxf(v2, v3));
#pragma unroll
      for (int mk = 1; mk < 16; mk <<= 1) mx = fmaxf(mx, __shfl_xor(mx, mk));
      float se = __expf(v0 - mx) + __expf(v1 - mx) + __expf(v2 - mx) + __expf(v3 - mx);
#pragma unroll
      for (int mk = 1; mk < 16; mk <<= 1) se += __shfl_xor(se, mk);
      if (q == 0){ pm[w][mt * 16 + 4 * r + rg] = mx; ps[w][mt * 16 + 4 * r + rg] = se; }
    }
  }
  __syncthreads();
  if (tid < 80){
    float m = pm[0][tid], s = ps[0][tid];
#pragma unroll
    for (int w2 = 1; w2 < 4; ++w2){
      float om = pm[w2][tid], os = ps[w2][tid];
      float M = fmaxf(m, om);
      s = s * __expf(m - M) + os * __expf(om - M);
      m = M;
    }
    mpart2[(size_t)(m0 + tid) * 125 + nslab] = m;
    spart2[(size_t)(m0 + tid) * 125 + nslab] = s;
  }
}

__global__ void k_comb2(const float* __restrict__ mpart2, const float* __restrict__ spart2,
                        const float* __restrict__ ltgt_all, const float* __restrict__ pg_all,
                        const float* __restrict__ cvl_all, const float* __restrict__ sct_all,
                        const int* __restrict__ tgt_ext, const float* __restrict__ lam,
                        float* __restrict__ loss_g, float* __restrict__ valid_g){
  int t = blockIdx.x; int tid = threadIdx.x;
  int b = tid >> 4, l16 = tid & 15;
  int row = t * 16 + b;
  float m = -1e30f, s = 0.f;
  for (int i = l16; i < 125; i += 16){
    float om = mpart2[(size_t)row * 125 + i], os = spart2[(size_t)row * 125 + i];
    float M = fmaxf(m, om);
    s = s * __expf(m - M) + os * __expf(om - M);
    m = M;
  }
#pragma unroll
  for (int mk = 1; mk < 16; mk <<= 1){
    float om = __shfl_xor(m, mk), os = __shfl_xor(s, mk);
    float M = fmaxf(m, om);
    s = s * __expf(m - M) + os * __expf(om - M);
    m = M;
  }
  if (l16 == 0){
    int tg = tgt_ext[b * 50 + t];
    float pv = (tg < 32000) ? (__expf(ltgt_all[row] - m) / s) : 0.f;
    float pg = pg_all[row];
    float pf = pg * pv + (1.f - pg) * sct_all[row];
    float sl = -__logf(pf + 1e-12f);
    float msk = (tg != 0) ? 1.f : 0.f;
    loss_g[row] = (sl + lam[0] * cvl_all[row]) * msk;
    valid_g[row] = msk;
  }
}

__global__ void k_final(const float* __restrict__ loss_g, const float* __restrict__ valid_g, float* __restrict__ out){
  __shared__ float r1[256], r2[256];
  int tid = threadIdx.x;
  float a = 0.f, v = 0.f;
  for (int i = tid; i < 800; i += 256){ a += loss_g[i]; v += valid_g[i]; }
  r1[tid] = a; r2[tid] = v; __syncthreads();
  for (int off = 128; off; off >>= 1){
    if (tid < off){ r1[tid] += r1[tid + off]; r2[tid] += r2[tid + off]; }
    __syncthreads();
  }
  if (tid == 0) out[0] = r1[0] / fmaxf(r2[0], 1.f);
}

extern "C" void kernel_launch(void* const* d_in, const int* in_sizes, int n_in,
                              void* d_out, int out_size, void* d_ws, size_t ws_size,
                              hipStream_t stream){
  const int*   src     = (const int*)  d_in[0];
  const int*   src_ext = (const int*)  d_in[1];
  const int*   dec_in  = (const int*)  d_in[2];
  const int*   tgt_ext = (const int*)  d_in[3];
  const float* enc_emb = (const float*)d_in[5];
  const float* eWihF   = (const float*)d_in[6];
  const float* eWhhF   = (const float*)d_in[7];
  const float* ebF     = (const float*)d_in[8];
  const float* eWihB   = (const float*)d_in[9];
  const float* eWhhB   = (const float*)d_in[10];
  const float* ebB     = (const float*)d_in[11];
  const float* rhW     = (const float*)d_in[12];
  const float* rhb     = (const float*)d_in[13];
  const float* rcW     = (const float*)d_in[14];
  const float* rcb     = (const float*)d_in[15];
  const float* dec_emb = (const float*)d_in[16];
  const float* dWih    = (const float*)d_in[17];
  const float* dWhh    = (const float*)d_in[18];
  const float* db_     = (const float*)d_in[19];
  const float* aWh     = (const float*)d_in[20];
  const float* aWs     = (const float*)d_in[21];
  const float* aWsb    = (const float*)d_in[22];
  const float* aWc     = (const float*)d_in[23];
  const float* av      = (const float*)d_in[24];
  const float* pgW     = (const float*)d_in[25];
  const float* pgb     = (const float*)d_in[26];
  const float* vW      = (const float*)d_in[27];
  const float* vb      = (const float*)d_in[28];
  const float* lam     = (const float*)d_in[29];
  const float* pgbias  = (const float*)d_in[30];
  (void)in_sizes; (void)n_in; (void)out_size; (void)ws_size;

  char* w = (char*)d_ws;
  size_t off = 0;
  auto alloc = [&](size_t bytes) -> char* {
    char* p = w + off; off += (bytes + 255) & ~(size_t)255; return p;
  };
  u16*     xw      = (u16*)    alloc(2ull * 400 * 1024 * 16 * 2);
  u16*     whhp    = (u16*)    alloc(2ull * 1024 * 256 * 2);
  ushort4* decwp   = (ushort4*)alloc(768ull * 256 * 8);
  u16*     enc_out = (u16*)    alloc(16ull * 400 * 512 * 2);
  u16*     feat    = (u16*)    alloc(16ull * 400 * 256 * 2);
  float*   hfin    = (float*)  alloc(2 * 16 * 256 * 4);
  float*   cfin    = (float*)  alloc(2 * 16 * 256 * 4);
  float*   h0buf   = (float*)  alloc(16 * 256 * 4);
  float*   c0buf   = (float*)  alloc(16 * 256 * 4);
  float4*  xwd     = (float4*) alloc(50ull * 16 * 256 * 16);
  float*   pg_emb  = (float*)  alloc(800 * 4);
  u32*     hpub    = (u32*)    alloc(8ull * 2048 * 4);   // 64KB (2 par x 2 dir x 2 bp)
  u32*     flags   = (u32*)    alloc(4 * 32 * 4);        // 512B
  u16*     Abf     = (u16*)    alloc(800ull * 768 * 2);
  float*   ltgt_all= (float*)  alloc(800 * 4);
  float*   pg_all  = (float*)  alloc(800 * 4);
  float*   cvl_all = (float*)  alloc(800 * 4);
  float*   sct_all = (float*)  alloc(800 * 4);
  float*   loss_g  = (float*)  alloc(800 * 4);
  float*   valid_g = (float*)  alloc(800 * 4);
  float*   mpart2  = (float*)  alloc(800ull * 125 * 4);
  float*   spart2  = (float*)  alloc(800ull * 125 * 4);
  u16*     vWt     = (u16*)    alloc(32000ull * 768 * 2);

  hipMemsetAsync(flags, 0, 4 * 32 * 4, stream);

  hipLaunchKernelGGL(k_pack_whh2, dim3(2048),  dim3(256), 0, stream, eWhhF, eWhhB, whhp);
  hipLaunchKernelGGL(k_pack_decw, dim3(768),   dim3(256), 0, stream, dWih, dWhh, decwp);
  hipLaunchKernelGGL(k_pack_vwt,  dim3(500, 12), dim3(256), 0, stream, vW, vWt);
  hipLaunchKernelGGL(k_enc_pre2,  dim3(800),   dim3(256), 0, stream, src, enc_emb, eWihF, ebF, eWihB, ebB, xw);
  hipLaunchKernelGGL(k_dec_pre,   dim3(800),   dim3(256), 0, stream, dec_in, dec_emb, dWih, db_, pgW, xwd, pg_emb);
  hipLaunchKernelGGL(k_enc_lstm4, dim3(4),     dim3(512), 0, stream, xw, whhp, enc_out, hfin, cfin, hpub, flags);
  hipLaunchKernelGGL(k_reduce,    dim3(16),    dim3(256), 0, stream, hfin, cfin, rhW, rhb, rcW, rcb, h0buf, c0buf);
  hipLaunchKernelGGL(k_encfeat,   dim3(400),   dim3(256), 0, stream, enc_out, aWh, feat);
  hipLaunchKernelGGL(k_dec_loop,  dim3(16),    dim3(1024), 0, stream,
                     decwp, xwd, h0buf, c0buf, feat, enc_out, src, src_ext, tgt_ext,
                     aWs, aWsb, aWc, av, pgW, pg_emb, pgb, pgbias,
                     Abf, pg_all, cvl_all, sct_all);
  hipLaunchKernelGGL(k_vgemm,  dim3(125, 10), dim3(256), 0, stream, Abf, vWt, vb, tgt_ext, mpart2, spart2, ltgt_all);
  hipLaunchKernelGGL(k_comb2,  dim3(50), dim3(256), 0, stream, mpart2, spart2, ltgt_all,
                     pg_all, cvl_all, sct_all, tgt_ext, lam, loss_g, valid_g);
  hipLaunchKernelGGL(k_final, dim3(1), dim3(256), 0, stream, loss_g, valid_g, (float*)d_out);
}